// Round 19
// baseline (530.651 us; speedup 1.0000x reference)
//
#include <hip/hip_runtime.h>

using bf16x8 = __attribute__((ext_vector_type(8))) short;
using f32x4  = __attribute__((ext_vector_type(4))) float;

#define DEV static __device__ __forceinline__

constexpr int SEQ    = 1040;
constexpr int MDIM   = 2048;
constexpr int NH     = 16;
constexpr int HD     = 128;
constexpr int NCACHE = 8320;
constexpr int LTOT   = NCACHE + SEQ;   // 9360
constexpr int NQT    = 17;             // ceil(SEQ/64)  (fallback kernel)
constexpr int NQT2   = 9;              // ceil(SEQ/128)

DEV float b2f(unsigned short u) {
  union { unsigned int i; float f; } z; z.i = ((unsigned int)u) << 16; return z.f;
}
DEV unsigned short f2b(float f) {
  union { float f; unsigned int i; } z; z.f = f;
  return (unsigned short)((z.i + 0x7fffu + ((z.i >> 16) & 1u)) >> 16);
}
DEV unsigned int cvtpk(float lo, float hi) {
  unsigned int r;
  asm("v_cvt_pk_bf16_f32 %0, %1, %2" : "=v"(r) : "v"(lo), "v"(hi));
  return r;
}
union U4S8 { uint4 u; short s[8]; };

// ---------- fused QKV GEMM v2: 64x128 tiles, grid (48, 17) (r18, passing) ----------
__global__ __launch_bounds__(256) void gemm_qkv_k(
    const float* __restrict__ x,
    const float* __restrict__ Wq, const float* __restrict__ Wk, const float* __restrict__ Wv,
    const float* __restrict__ bq, const float* __restrict__ bk, const float* __restrict__ bv,
    unsigned short* __restrict__ Qb, unsigned short* __restrict__ Kn, unsigned short* __restrict__ Vn) {
  __shared__ short As[64][40];
  __shared__ short Bs[128][40];
  const int tid = threadIdx.x;
  const int l = tid & 63, wv = tid >> 6;
  const int l16 = l & 15, kl = l >> 4;
  const int m0 = blockIdx.y * 64;
  const int n0g = blockIdx.x * 128;
  const int which = n0g >> 11;
  const int n0 = n0g & 2047;
  const float* W = (which == 0) ? Wq : (which == 1) ? Wk : Wv;
  const float* bias = (which == 0) ? bq : (which == 1) ? bk : bv;
  unsigned short* outp = (which == 0) ? Qb : (which == 1) ? Kn : Vn;
  const int wm = (wv >> 1) * 32, wn = (wv & 1) * 64;
  const int nq = tid >> 4, kh = tid & 15;
  f32x4 acc[2][4] = {};
  for (int k0 = 0; k0 < MDIM; k0 += 32) {
    {
      int m = tid >> 2, kq = tid & 3;
      int row = m0 + m, k = k0 + kq * 8;
      U4S8 v; v.u = make_uint4(0, 0, 0, 0);
      if (row < SEQ) {
        const float* Af = x + (size_t)row * MDIM + k;
        f32x4 f0 = *(const f32x4*)(Af);
        f32x4 f1 = *(const f32x4*)(Af + 4);
        v.u = make_uint4(cvtpk(f0[0], f0[1]), cvtpk(f0[2], f0[3]),
                         cvtpk(f1[0], f1[1]), cvtpk(f1[2], f1[3]));
      }
      *(uint4*)&As[m][kq * 8] = v.u;
    }
    {
      const float* Wp = W + (size_t)(k0 + kh * 2) * MDIM + n0 + nq * 8;
      f32x4 a0 = *(const f32x4*)(Wp);
      f32x4 a1 = *(const f32x4*)(Wp + 4);
      f32x4 b0 = *(const f32x4*)(Wp + MDIM);
      f32x4 b1 = *(const f32x4*)(Wp + MDIM + 4);
#pragma unroll
      for (int i = 0; i < 4; ++i) {
        *(unsigned int*)&Bs[nq * 8 + i][kh * 2] = cvtpk(a0[i], b0[i]);
        *(unsigned int*)&Bs[nq * 8 + 4 + i][kh * 2] = cvtpk(a1[i], b1[i]);
      }
    }
    __syncthreads();
    bf16x8 aF[2], bF[4];
#pragma unroll
    for (int mi = 0; mi < 2; ++mi)
      aF[mi] = *(const bf16x8*)&As[wm + mi * 16 + l16][kl * 8];
#pragma unroll
    for (int ni = 0; ni < 4; ++ni)
      bF[ni] = *(const bf16x8*)&Bs[wn + ni * 16 + l16][kl * 8];
#pragma unroll
    for (int mi = 0; mi < 2; ++mi)
#pragma unroll
      for (int ni = 0; ni < 4; ++ni)
        acc[mi][ni] = __builtin_amdgcn_mfma_f32_16x16x32_bf16(
            aF[mi], bF[ni], acc[mi][ni], 0, 0, 0);
    __syncthreads();
  }
#pragma unroll
  for (int ni = 0; ni < 4; ++ni) {
    const int col = n0 + wn + ni * 16 + l16;
    const float bb = bias[col];
#pragma unroll
    for (int mi = 0; mi < 2; ++mi) {
      const int rowb = m0 + wm + mi * 16 + kl * 4;
#pragma unroll
      for (int r = 0; r < 4; ++r) {
        const int row = rowb + r;
        if (row >= SEQ) continue;
        outp[((size_t)(col >> 7) * SEQ + row) * HD + (col & 127)] = f2b(acc[mi][ni][r] + bb);
      }
    }
  }
}

// ---------- GEMM for Wo v2: 64x128 tiles (r18, passing) ----------
__global__ __launch_bounds__(256) void gemm_k(
    const void* __restrict__ Ap, const float* __restrict__ W,
    const float* __restrict__ bias, void* __restrict__ outp,
    int aLay, int oMode) {
  __shared__ short As[64][40];
  __shared__ short Bs[128][40];
  const int tid = threadIdx.x;
  const int l = tid & 63, wv = tid >> 6;
  const int l16 = l & 15, kl = l >> 4;
  const int m0 = blockIdx.y * 64, n0 = blockIdx.x * 128;
  const int wm = (wv >> 1) * 32, wn = (wv & 1) * 64;
  const int nq = tid >> 4, kh = tid & 15;
  f32x4 acc[2][4] = {};
  for (int k0 = 0; k0 < MDIM; k0 += 32) {
    {
      int m = tid >> 2, kq = tid & 3;
      int row = m0 + m, k = k0 + kq * 8;
      bf16x8 v = {0, 0, 0, 0, 0, 0, 0, 0};
      if (row < SEQ) {
        if (aLay == 0) {
          const float* Af = (const float*)Ap + (size_t)row * MDIM + k;
          f32x4 f0 = *(const f32x4*)(Af);
          f32x4 f1 = *(const f32x4*)(Af + 4);
          U4S8 u; u.u = make_uint4(cvtpk(f0[0], f0[1]), cvtpk(f0[2], f0[3]),
                                   cvtpk(f1[0], f1[1]), cvtpk(f1[2], f1[3]));
#pragma unroll
          for (int i = 0; i < 8; ++i) v[i] = u.s[i];
        } else {
          const unsigned short* Ab = (const unsigned short*)Ap;
          v = *(const bf16x8*)(Ab + ((size_t)(k >> 7) * SEQ + row) * HD + (k & 127));
        }
      }
      *(bf16x8*)&As[m][kq * 8] = v;
    }
    {
      const float* Wp = W + (size_t)(k0 + kh * 2) * MDIM + n0 + nq * 8;
      f32x4 a0 = *(const f32x4*)(Wp);
      f32x4 a1 = *(const f32x4*)(Wp + 4);
      f32x4 b0 = *(const f32x4*)(Wp + MDIM);
      f32x4 b1 = *(const f32x4*)(Wp + MDIM + 4);
#pragma unroll
      for (int i = 0; i < 4; ++i) {
        *(unsigned int*)&Bs[nq * 8 + i][kh * 2] = cvtpk(a0[i], b0[i]);
        *(unsigned int*)&Bs[nq * 8 + 4 + i][kh * 2] = cvtpk(a1[i], b1[i]);
      }
    }
    __syncthreads();
    bf16x8 aF[2], bF[4];
#pragma unroll
    for (int mi = 0; mi < 2; ++mi)
      aF[mi] = *(const bf16x8*)&As[wm + mi * 16 + l16][kl * 8];
#pragma unroll
    for (int ni = 0; ni < 4; ++ni)
      bF[ni] = *(const bf16x8*)&Bs[wn + ni * 16 + l16][kl * 8];
#pragma unroll
    for (int mi = 0; mi < 2; ++mi)
#pragma unroll
      for (int ni = 0; ni < 4; ++ni)
        acc[mi][ni] = __builtin_amdgcn_mfma_f32_16x16x32_bf16(
            aF[mi], bF[ni], acc[mi][ni], 0, 0, 0);
    __syncthreads();
  }
#pragma unroll
  for (int ni = 0; ni < 4; ++ni) {
    const int col = n0 + wn + ni * 16 + l16;
    const float bb = bias[col];
#pragma unroll
    for (int mi = 0; mi < 2; ++mi) {
      const int rowb = m0 + wm + mi * 16 + kl * 4;
#pragma unroll
      for (int r = 0; r < 4; ++r) {
        const int row = rowb + r;
        if (row >= SEQ) continue;
        const float val = acc[mi][ni][r] + bb;
        if (oMode == 2) {
          ((unsigned short*)outp)[((size_t)(col >> 7) * SEQ + row) * HD + (col & 127)] = f2b(val);
        } else {
          ((float*)outp)[(size_t)row * MDIM + col] = val;
        }
      }
    }
  }
}

// ---------- RMSNorm + RoPE (unchanged, passing) ----------
__global__ __launch_bounds__(256) void rmsrope_k(
    unsigned short* __restrict__ Qb, unsigned short* __restrict__ Kn,
    const float* __restrict__ gq, const float* __restrict__ gk,
    const float* __restrict__ fr) {
  const int s = blockIdx.x, which = blockIdx.y;
  unsigned short* B = which ? Kn : Qb;
  const float* g = which ? gk : gq;
  __shared__ float cs[64], sn[64], red[4];
  const int t = threadIdx.x;
  if (t < 64) {
    float a = fr[s * 64 + t];
    cs[t] = cosf(a);
    sn[t] = sinf(a);
  }
  const int c0 = t * 8;
  const int hh = c0 >> 7, dd = c0 & 127, p0 = dd >> 1;
  const size_t addr = ((size_t)hh * SEQ + s) * HD + dd;
  bf16x8 v = *(const bf16x8*)(B + addr);
  float y[8];
#pragma unroll
  for (int i = 0; i < 8; ++i) y[i] = b2f((unsigned short)v[i]);
  float ssq = 0.f;
#pragma unroll
  for (int i = 0; i < 8; ++i) ssq += y[i] * y[i];
#pragma unroll
  for (int off = 32; off; off >>= 1) ssq += __shfl_xor(ssq, off);
  if ((t & 63) == 0) red[t >> 6] = ssq;
  __syncthreads();
  const float var = (red[0] + red[1] + red[2] + red[3]) * (1.0f / MDIM);
  const float rs = rsqrtf(var + 1e-6f);
  bf16x8 ov;
#pragma unroll
  for (int i = 0; i < 4; ++i) {
    float e = b2f(f2b(y[2 * i] * rs)) * g[c0 + 2 * i];
    float o = b2f(f2b(y[2 * i + 1] * rs)) * g[c0 + 2 * i + 1];
    float C = cs[p0 + i], S = sn[p0 + i];
    ov[2 * i]     = (short)f2b(e * C - o * S);
    ov[2 * i + 1] = (short)f2b(e * S + o * C);
  }
  *(bf16x8*)(B + addr) = ov;
}

// ---------- flash attention v5: QBLK=128, 8 waves, LDS double-buffered K/V,
//            2 barriers/tile. Pl (cols=64, wave-private) aliases Kl[cur]. ----------
__global__ __launch_bounds__(512) void attn_part5_k(
    const unsigned short* __restrict__ Qb, const unsigned short* __restrict__ Kn,
    const unsigned short* __restrict__ Vn, const float* __restrict__ Kc,
    const float* __restrict__ Vc, float* __restrict__ Opart,
    float* __restrict__ ml, int chunk, int S) {
  __shared__ short Kl2[2][64 * 136];   // 2 x 17.4 KB
  __shared__ short Vt2[2][128 * 72];   // 2 x 18.4 KB   (total 71.7 KB)
  const int b = blockIdx.x;
  const int xcd = b & 7;
  const int r_ = b >> 3;
  const int qt = r_ % NQT2;
  const int g = (r_ / NQT2) * 8 + xcd;   // group id = z*NH + h
  const int h = g & (NH - 1);
  const int z = g >> 4;
  const int tid = threadIdx.x, wv = tid >> 6, l = tid & 63;
  const int l16 = l & 15, kl = l >> 4;
  const float SCALE = 0.08838834764831845f;

  const int c0 = z * chunk;
  const int cend = min(c0 + chunk, LTOT);

  int qrow = qt * 128 + wv * 16 + l16;
  if (qrow > SEQ - 1) qrow = SEQ - 1;
  bf16x8 qf[4];
#pragma unroll
  for (int kk = 0; kk < 4; ++kk)
    qf[kk] = *(const bf16x8*)(Qb + ((size_t)h * SEQ + qrow) * HD + kk * 32 + kl * 8);

  f32x4 oacc[8] = {};
  float mrow[4] = {-1e30f, -1e30f, -1e30f, -1e30f};
  float lrow[4] = {0.f, 0.f, 0.f, 0.f};

  const int j0 = tid & 63, dq0 = tid >> 6, dq1 = (tid + 512) >> 6;

  // stage KV tile at kv into (dstK, dstV)
  auto STAGE = [&](int kv, short* dstK, short* dstV) {
#pragma unroll
    for (int it = 0; it < 2; ++it) {
      const int dq = (it == 0) ? dq0 : dq1;
      const int jg = kv + j0;
      U4S8 ku, vu;
      ku.u = make_uint4(0, 0, 0, 0);
      vu.u = make_uint4(0, 0, 0, 0);
      if (jg < NCACHE) {
        const float* kp = Kc + ((size_t)jg * NH + h) * HD + dq * 8;
        const float* vp = Vc + ((size_t)jg * NH + h) * HD + dq * 8;
        f32x4 ka = *(const f32x4*)(kp), kb = *(const f32x4*)(kp + 4);
        f32x4 va = *(const f32x4*)(vp), vb = *(const f32x4*)(vp + 4);
        ku.u = make_uint4(cvtpk(ka[0], ka[1]), cvtpk(ka[2], ka[3]),
                          cvtpk(kb[0], kb[1]), cvtpk(kb[2], kb[3]));
        vu.u = make_uint4(cvtpk(va[0], va[1]), cvtpk(va[2], va[3]),
                          cvtpk(vb[0], vb[1]), cvtpk(vb[2], vb[3]));
      } else if (jg < LTOT) {
        ku.u = *(const uint4*)(Kn + ((size_t)h * SEQ + (jg - NCACHE)) * HD + dq * 8);
        vu.u = *(const uint4*)(Vn + ((size_t)h * SEQ + (jg - NCACHE)) * HD + dq * 8);
      }
      *(uint4*)&dstK[j0 * 136 + dq * 8] = ku.u;
#pragma unroll
      for (int i = 0; i < 8; ++i) dstV[(dq * 8 + i) * 72 + j0] = vu.s[i];
    }
  };

  // one KV-64 tile: compute from (curK,curV), stage kv+64 into (nxtK,nxtV)
  auto TILE = [&](int kv0, short* curK, short* curV, short* nxtK, short* nxtV) {
    if (kv0 + 64 < cend) STAGE(kv0 + 64, nxtK, nxtV);

    // ---- S = Q K^T from curK
    f32x4 sa[4] = {};
#pragma unroll
    for (int ni = 0; ni < 4; ++ni)
#pragma unroll
      for (int kk = 0; kk < 4; ++kk) {
        bf16x8 bK = *(const bf16x8*)&curK[(ni * 16 + l16) * 136 + kk * 32 + kl * 8];
        sa[ni] = __builtin_amdgcn_mfma_f32_16x16x32_bf16(qf[kk], bK, sa[ni], 0, 0, 0);
      }
    __syncthreads();   // bar_a: all QK reads of curK done (P aliases curK)

    // ---- online softmax
    float sv[4][4];
    float pm[4] = {-1e30f, -1e30f, -1e30f, -1e30f};
#pragma unroll
    for (int ni = 0; ni < 4; ++ni) {
      int jg = kv0 + ni * 16 + l16;
      bool valid = jg < LTOT;
#pragma unroll
      for (int r = 0; r < 4; ++r) {
        float xs = valid ? sa[ni][r] * SCALE : -1e30f;
        sv[ni][r] = xs;
        pm[r] = fmaxf(pm[r], xs);
      }
    }
#pragma unroll
    for (int off = 1; off < 16; off <<= 1)
#pragma unroll
      for (int r = 0; r < 4; ++r) pm[r] = fmaxf(pm[r], __shfl_xor(pm[r], off));

    float sc[4];
#pragma unroll
    for (int r = 0; r < 4; ++r) {
      float mn = fmaxf(mrow[r], pm[r]);
      sc[r] = __expf(mrow[r] - mn);
      mrow[r] = mn;
    }
    float ps[4] = {0.f, 0.f, 0.f, 0.f};
#pragma unroll
    for (int ni = 0; ni < 4; ++ni)
#pragma unroll
      for (int r = 0; r < 4; ++r) {
        float p = __expf(sv[ni][r] - mrow[r]);
        sv[ni][r] = p;
        ps[r] += p;
      }
#pragma unroll
    for (int off = 1; off < 16; off <<= 1)
#pragma unroll
      for (int r = 0; r < 4; ++r) ps[r] += __shfl_xor(ps[r], off);
#pragma unroll
    for (int r = 0; r < 4; ++r) lrow[r] = lrow[r] * sc[r] + ps[r];
#pragma unroll
    for (int di = 0; di < 8; ++di)
#pragma unroll
      for (int r = 0; r < 4; ++r) oacc[di][r] *= sc[r];

    // ---- P write into curK (wave-private Pl, cols=64) ; then PV (no barrier)
#pragma unroll
    for (int ni = 0; ni < 4; ++ni)
#pragma unroll
      for (int r = 0; r < 4; ++r)
        curK[(wv * 16 + kl * 4 + r) * 64 + ni * 16 + l16] = (short)f2b(sv[ni][r]);

#pragma unroll
    for (int di = 0; di < 8; ++di)
#pragma unroll
      for (int k2 = 0; k2 < 2; ++k2) {
        bf16x8 aP = *(const bf16x8*)&curK[(wv * 16 + l16) * 64 + k2 * 32 + kl * 8];
        bf16x8 bV = *(const bf16x8*)&curV[(di * 16 + l16) * 72 + k2 * 32 + kl * 8];
        oacc[di] = __builtin_amdgcn_mfma_f32_16x16x32_bf16(aP, bV, oacc[di], 0, 0, 0);
      }
    __syncthreads();   // bar_b: stage of nxt visible; curK/curV free for reuse
  };

  STAGE(c0, Kl2[0], Vt2[0]);
  __syncthreads();

  for (int kv0 = c0; kv0 < cend; kv0 += 128) {
    TILE(kv0, Kl2[0], Vt2[0], Kl2[1], Vt2[1]);
    if (kv0 + 64 < cend)
      TILE(kv0 + 64, Kl2[1], Vt2[1], Kl2[0], Vt2[0]);
  }

  const size_t pbase = (((size_t)z * NH + h) * NQT2 + qt);
  const int row = wv * 16 + kl * 4;
#pragma unroll
  for (int r = 0; r < 4; ++r) {
    float* Op = Opart + (pbase * 128 + row + r) * HD;
#pragma unroll
    for (int di = 0; di < 8; ++di) Op[di * 16 + l16] = oacc[di][r];
    ml[(pbase * 2 + 0) * 128 + row + r] = mrow[r];
    ml[(pbase * 2 + 1) * 128 + row + r] = lrow[r];
  }
}

// ---------- merge partials (QBLK=128) -> bf16 O in Qb (unchanged, passing) ----------
__global__ __launch_bounds__(512) void attn_merge2_k(
    const float* __restrict__ Opart, const float* __restrict__ ml,
    unsigned short* __restrict__ Qb, int S) {
  const int qt = blockIdx.x, h = blockIdx.y;
  const int t = threadIdx.x;
  const int row = t >> 2, d0 = (t & 3) * 32;
  const int q = qt * 128 + row;

  float M = -1e30f;
  for (int s = 0; s < S; ++s) {
    const size_t pbase = (((size_t)s * NH + h) * NQT2 + qt);
    M = fmaxf(M, ml[(pbase * 2 + 0) * 128 + row]);
  }
  float L = 0.f;
  float o[32];
#pragma unroll
  for (int i = 0; i < 32; ++i) o[i] = 0.f;
  for (int s = 0; s < S; ++s) {
    const size_t pbase = (((size_t)s * NH + h) * NQT2 + qt);
    const float ms = ml[(pbase * 2 + 0) * 128 + row];
    const float ls = ml[(pbase * 2 + 1) * 128 + row];
    const float w = __expf(ms - M);
    L += w * ls;
    const float* Op = Opart + (pbase * 128 + row) * HD + d0;
#pragma unroll
    for (int c = 0; c < 8; ++c) {
      f32x4 v = *(const f32x4*)(Op + c * 4);
#pragma unroll
      for (int i = 0; i < 4; ++i) o[c * 4 + i] += w * v[i];
    }
  }
  if (q < SEQ) {
    const float inv = 1.f / L;
    unsigned short* op = Qb + ((size_t)h * SEQ + q) * HD + d0;
#pragma unroll
    for (int i = 0; i < 32; ++i) op[i] = f2b(o[i] * inv);
  }
}

// ---------- fallback single-pass attention (known-passing, untouched) ----------
__global__ __launch_bounds__(256) void attn_k(
    unsigned short* __restrict__ Qb, const unsigned short* __restrict__ Kn,
    const unsigned short* __restrict__ Vn, const float* __restrict__ Kc,
    const float* __restrict__ Vc) {
  __shared__ short Kl[64][136];
  __shared__ short Vt[128][72];
  __shared__ short Pl[4][16][72];
  const int h = blockIdx.y, qt = blockIdx.x;
  const int tid = threadIdx.x, wv = tid >> 6, l = tid & 63;
  const int l16 = l & 15, kl = l >> 4;
  const float SCALE = 0.08838834764831845f;

  int qrow = qt * 64 + wv * 16 + l16;
  if (qrow > SEQ - 1) qrow = SEQ - 1;
  bf16x8 qf[4];
#pragma unroll
  for (int kk = 0; kk < 4; ++kk)
    qf[kk] = *(const bf16x8*)(Qb + ((size_t)h * SEQ + qrow) * HD + kk * 32 + kl * 8);

  f32x4 oacc[8] = {};
  float mrow[4] = {-1e30f, -1e30f, -1e30f, -1e30f};
  float lrow[4] = {0.f, 0.f, 0.f, 0.f};

  for (int kv0 = 0; kv0 < LTOT; kv0 += 64) {
#pragma unroll
    for (int it = 0; it < 4; ++it) {
      int slot = tid + it * 256;
      int j = slot & 63, dq = slot >> 6;
      int jg = kv0 + j;
      bf16x8 kvv = {0,0,0,0,0,0,0,0}, vvv = {0,0,0,0,0,0,0,0};
      if (jg < NCACHE) {
        const float* kp = Kc + ((size_t)jg * NH + h) * HD + dq * 8;
        const float* vp = Vc + ((size_t)jg * NH + h) * HD + dq * 8;
        f32x4 ka = *(const f32x4*)(kp), kb = *(const f32x4*)(kp + 4);
        f32x4 va = *(const f32x4*)(vp), vb = *(const f32x4*)(vp + 4);
#pragma unroll
        for (int i = 0; i < 4; ++i) {
          kvv[i] = (short)f2b(ka[i]); kvv[4 + i] = (short)f2b(kb[i]);
          vvv[i] = (short)f2b(va[i]); vvv[4 + i] = (short)f2b(vb[i]);
        }
      } else if (jg < LTOT) {
        kvv = *(const bf16x8*)(Kn + ((size_t)h * SEQ + (jg - NCACHE)) * HD + dq * 8);
        vvv = *(const bf16x8*)(Vn + ((size_t)h * SEQ + (jg - NCACHE)) * HD + dq * 8);
      }
      *(bf16x8*)&Kl[j][dq * 8] = kvv;
#pragma unroll
      for (int i = 0; i < 8; ++i) Vt[dq * 8 + i][j] = vvv[i];
    }
    __syncthreads();

    f32x4 sa[4] = {};
#pragma unroll
    for (int ni = 0; ni < 4; ++ni)
#pragma unroll
      for (int kk = 0; kk < 4; ++kk) {
        bf16x8 bK = *(const bf16x8*)&Kl[ni * 16 + l16][kk * 32 + kl * 8];
        sa[ni] = __builtin_amdgcn_mfma_f32_16x16x32_bf16(qf[kk], bK, sa[ni], 0, 0, 0);
      }

    float sv[4][4];
    float pm[4] = {-1e30f, -1e30f, -1e30f, -1e30f};
#pragma unroll
    for (int ni = 0; ni < 4; ++ni) {
      int jg = kv0 + ni * 16 + l16;
      bool valid = jg < LTOT;
#pragma unroll
      for (int r = 0; r < 4; ++r) {
        float xs = valid ? sa[ni][r] * SCALE : -1e30f;
        sv[ni][r] = xs;
        pm[r] = fmaxf(pm[r], xs);
      }
    }
#pragma unroll
    for (int off = 1; off < 16; off <<= 1)
#pragma unroll
      for (int r = 0; r < 4; ++r) pm[r] = fmaxf(pm[r], __shfl_xor(pm[r], off));

    float sc[4];
#pragma unroll
    for (int r = 0; r < 4; ++r) {
      float mn = fmaxf(mrow[r], pm[r]);
      sc[r] = __expf(mrow[r] - mn);
      mrow[r] = mn;
    }
    float ps[4] = {0.f, 0.f, 0.f, 0.f};
#pragma unroll
    for (int ni = 0; ni < 4; ++ni)
#pragma unroll
      for (int r = 0; r < 4; ++r) {
        float p = __expf(sv[ni][r] - mrow[r]);
        sv[ni][r] = p;
        ps[r] += p;
      }
#pragma unroll
    for (int off = 1; off < 16; off <<= 1)
#pragma unroll
      for (int r = 0; r < 4; ++r) ps[r] += __shfl_xor(ps[r], off);
#pragma unroll
    for (int r = 0; r < 4; ++r) lrow[r] = lrow[r] * sc[r] + ps[r];
#pragma unroll
    for (int di = 0; di < 8; ++di)
#pragma unroll
      for (int r = 0; r < 4; ++r) oacc[di][r] *= sc[r];
#pragma unroll
    for (int ni = 0; ni < 4; ++ni)
#pragma unroll
      for (int r = 0; r < 4; ++r)
        Pl[wv][kl * 4 + r][ni * 16 + l16] = (short)f2b(sv[ni][r]);
    __syncthreads();

#pragma unroll
    for (int di = 0; di < 8; ++di)
#pragma unroll
      for (int k2 = 0; k2 < 2; ++k2) {
        bf16x8 aP = *(const bf16x8*)&Pl[wv][l16][k2 * 32 + kl * 8];
        bf16x8 bV = *(const bf16x8*)&Vt[di * 16 + l16][k2 * 32 + kl * 8];
        oacc[di] = __builtin_amdgcn_mfma_f32_16x16x32_bf16(aP, bV, oacc[di], 0, 0, 0);
      }
    __syncthreads();
  }

  const int qb = qt * 64 + wv * 16 + kl * 4;
#pragma unroll
  for (int r = 0; r < 4; ++r) {
    int q = qb + r;
    if (q < SEQ) {
      float inv = 1.0f / lrow[r];
#pragma unroll
      for (int di = 0; di < 8; ++di)
        Qb[((size_t)h * SEQ + q) * HD + di * 16 + l16] = f2b(oacc[di][r] * inv);
    }
  }
}

extern "C" void kernel_launch(void* const* d_in, const int* in_sizes, int n_in,
                              void* d_out, int out_size, void* d_ws, size_t ws_size,
                              hipStream_t stream) {
  const float* x  = (const float*)d_in[0];
  const float* fr = (const float*)d_in[2];
  const float* Kc = (const float*)d_in[3];
  const float* Vc = (const float*)d_in[4];
  const float* Wq = (const float*)d_in[5];
  const float* bq = (const float*)d_in[6];
  const float* Wk = (const float*)d_in[7];
  const float* bk = (const float*)d_in[8];
  const float* Wv = (const float*)d_in[9];
  const float* bv = (const float*)d_in[10];
  const float* Wo = (const float*)d_in[11];
  const float* bo = (const float*)d_in[12];
  const float* gq = (const float*)d_in[13];
  const float* gk = (const float*)d_in[14];

  unsigned short* Qb = (unsigned short*)d_ws;
  unsigned short* Kn = Qb + (size_t)NH * SEQ * HD;
  unsigned short* Vn = Kn + (size_t)NH * SEQ * HD;
  const size_t baseB = (size_t)3 * NH * SEQ * HD * 2;

  const size_t perSplitB = (size_t)NH * NQT2 * 128 * HD * 4
                         + (size_t)NH * NQT2 * 2 * 128 * 4;
  int S = 0;
  if (ws_size >= baseB + 8 * perSplitB + (1 << 20)) S = 8;
  else if (ws_size >= baseB + 7 * perSplitB + (1 << 20)) S = 7;
  else if (ws_size >= baseB + 4 * perSplitB + (1 << 20)) S = 4;

  gemm_qkv_k<<<dim3(48, 17), 256, 0, stream>>>(x, Wq, Wk, Wv, bq, bk, bv, Qb, Kn, Vn);
  rmsrope_k<<<dim3(SEQ, 2), 256, 0, stream>>>(Qb, Kn, gq, gk, fr);

  if (S > 0) {
    float* Opart = (float*)((char*)d_ws + baseB);
    float* ml    = Opart + (size_t)S * NH * NQT2 * 128 * HD;
    const int tiles = (LTOT + 63) / 64;                // 147
    const int chunk = ((tiles + S - 1) / S) * 64;
    attn_part5_k<<<dim3(NQT2 * NH * S), 512, 0, stream>>>(Qb, Kn, Vn, Kc, Vc, Opart, ml, chunk, S);
    attn_merge2_k<<<dim3(NQT2, NH), 512, 0, stream>>>(Opart, ml, Qb, S);
  } else {
    attn_k<<<dim3(NQT, NH), 256, 0, stream>>>(Qb, Kn, Vn, Kc, Vc);
  }

  gemm_k<<<dim3(16, 17), 256, 0, stream>>>(Qb, Wo, bo, d_out, 1, 3);
}

// Round 20
// 429.799 us; speedup vs baseline: 1.2346x; 1.2346x over previous
//
#include <hip/hip_runtime.h>

using bf16x8 = __attribute__((ext_vector_type(8))) short;
using f32x4  = __attribute__((ext_vector_type(4))) float;

#define DEV static __device__ __forceinline__

constexpr int SEQ    = 1040;
constexpr int MDIM   = 2048;
constexpr int NH     = 16;
constexpr int HD     = 128;
constexpr int NCACHE = 8320;
constexpr int LTOT   = NCACHE + SEQ;   // 9360
constexpr int NQT    = 17;             // fallback kernel
constexpr int NQT2   = 9;              // ceil(SEQ/128)

DEV float b2f(unsigned short u) {
  union { unsigned int i; float f; } z; z.i = ((unsigned int)u) << 16; return z.f;
}
DEV unsigned short f2b(float f) {
  union { float f; unsigned int i; } z; z.f = f;
  return (unsigned short)((z.i + 0x7fffu + ((z.i >> 16) & 1u)) >> 16);
}
DEV unsigned int cvtpk(float lo, float hi) {
  unsigned int r;
  asm("v_cvt_pk_bf16_f32 %0, %1, %2" : "=v"(r) : "v"(lo), "v"(hi));
  return r;
}
union U4S8 { uint4 u; short s[8]; };

// ---------- convert x fp32 -> bf16 ----------
__global__ __launch_bounds__(256) void convx_k(
    const float* __restrict__ x, unsigned short* __restrict__ xb, int n8) {
  int i = blockIdx.x * 256 + threadIdx.x;
  if (i < n8) {
    const float* p = x + (size_t)i * 8;
    f32x4 a = *(const f32x4*)p, b = *(const f32x4*)(p + 4);
    uint4 u = make_uint4(cvtpk(a[0], a[1]), cvtpk(a[2], a[3]),
                         cvtpk(b[0], b[1]), cvtpk(b[2], b[3]));
    *(uint4*)(xb + (size_t)i * 8) = u;
  }
}

// ---------- convert+transpose W [k][n] fp32 -> Wt [n][k] bf16 (4 weights via z) ----------
__global__ __launch_bounds__(256) void convt_k(
    const float* __restrict__ W0, const float* __restrict__ W1,
    const float* __restrict__ W2, const float* __restrict__ W3,
    unsigned short* __restrict__ T0, unsigned short* __restrict__ T1,
    unsigned short* __restrict__ T2, unsigned short* __restrict__ T3) {
  __shared__ short T[64][72];
  const int zz = blockIdx.z;
  const float* W = (zz == 0) ? W0 : (zz == 1) ? W1 : (zz == 2) ? W2 : W3;
  unsigned short* O = (zz == 0) ? T0 : (zz == 1) ? T1 : (zz == 2) ? T2 : T3;
  const int r0 = blockIdx.y * 64, c0 = blockIdx.x * 64;
  const int t = threadIdx.x;
  {
    int row = t >> 2, cq = t & 3;
    const float* p = W + (size_t)(r0 + row) * MDIM + c0 + cq * 16;
    f32x4 a = *(const f32x4*)(p);
    f32x4 b = *(const f32x4*)(p + 4);
    f32x4 c = *(const f32x4*)(p + 8);
    f32x4 d = *(const f32x4*)(p + 12);
    *(uint4*)&T[row][cq * 16] =
        make_uint4(cvtpk(a[0], a[1]), cvtpk(a[2], a[3]), cvtpk(b[0], b[1]), cvtpk(b[2], b[3]));
    *(uint4*)&T[row][cq * 16 + 8] =
        make_uint4(cvtpk(c[0], c[1]), cvtpk(c[2], c[3]), cvtpk(d[0], d[1]), cvtpk(d[2], d[3]));
  }
  __syncthreads();
  {
    int c = t >> 2, kq = t & 3;
    U4S8 v0, v1;
#pragma unroll
    for (int i = 0; i < 8; ++i) v0.s[i] = T[kq * 16 + i][c];
#pragma unroll
    for (int i = 0; i < 8; ++i) v1.s[i] = T[kq * 16 + 8 + i][c];
    unsigned short* op = O + (size_t)(c0 + c) * MDIM + r0 + kq * 16;
    *(uint4*)(op) = v0.u;
    *(uint4*)(op + 8) = v1.u;
  }
}

// ---------- fused QKV GEMM v3: 64x128 tiles, BK=64, bf16 inputs ----------
__global__ __launch_bounds__(256) void gemm_qkv_k(
    const unsigned short* __restrict__ xb,
    const unsigned short* __restrict__ Wtq, const unsigned short* __restrict__ Wtk,
    const unsigned short* __restrict__ Wtv,
    const float* __restrict__ bq, const float* __restrict__ bk, const float* __restrict__ bv,
    unsigned short* __restrict__ Qb, unsigned short* __restrict__ Kn, unsigned short* __restrict__ Vn) {
  __shared__ short As[64][72];
  __shared__ short Bs[128][72];
  const int tid = threadIdx.x;
  const int l = tid & 63, wv = tid >> 6;
  const int l16 = l & 15, kl = l >> 4;
  const int m0 = blockIdx.y * 64;
  const int n0g = blockIdx.x * 128;
  const int which = n0g >> 11;
  const int n0 = n0g & 2047;
  const unsigned short* Wt = (which == 0) ? Wtq : (which == 1) ? Wtk : Wtv;
  const float* bias = (which == 0) ? bq : (which == 1) ? bk : bv;
  unsigned short* outp = (which == 0) ? Qb : (which == 1) ? Kn : Vn;
  const int wm = (wv >> 1) * 32, wn = (wv & 1) * 64;
  f32x4 acc[2][4] = {};
  for (int k0 = 0; k0 < MDIM; k0 += 64) {
    {  // A: 64x64 bf16, thread: m=t>>2, kq=t&3 (16 k)
      int m = tid >> 2, kq = tid & 3;
      int row = m0 + m;
      uint4 v0 = make_uint4(0, 0, 0, 0), v1 = make_uint4(0, 0, 0, 0);
      if (row < SEQ) {
        const unsigned short* p = xb + (size_t)row * MDIM + k0 + kq * 16;
        v0 = *(const uint4*)p;
        v1 = *(const uint4*)(p + 8);
      }
      *(uint4*)&As[m][kq * 16] = v0;
      *(uint4*)&As[m][kq * 16 + 8] = v1;
    }
    {  // B: 128x64 bf16, thread: n=t>>1, kq=t&1 (32 k)
      int n = tid >> 1, kq = tid & 1;
      const unsigned short* p = Wt + (size_t)(n0 + n) * MDIM + k0 + kq * 32;
      uint4 v0 = *(const uint4*)p, v1 = *(const uint4*)(p + 8);
      uint4 v2 = *(const uint4*)(p + 16), v3 = *(const uint4*)(p + 24);
      *(uint4*)&Bs[n][kq * 32] = v0;
      *(uint4*)&Bs[n][kq * 32 + 8] = v1;
      *(uint4*)&Bs[n][kq * 32 + 16] = v2;
      *(uint4*)&Bs[n][kq * 32 + 24] = v3;
    }
    __syncthreads();
#pragma unroll
    for (int kk = 0; kk < 2; ++kk) {
      bf16x8 aF[2], bF[4];
#pragma unroll
      for (int mi = 0; mi < 2; ++mi)
        aF[mi] = *(const bf16x8*)&As[wm + mi * 16 + l16][kk * 32 + kl * 8];
#pragma unroll
      for (int ni = 0; ni < 4; ++ni)
        bF[ni] = *(const bf16x8*)&Bs[wn + ni * 16 + l16][kk * 32 + kl * 8];
#pragma unroll
      for (int mi = 0; mi < 2; ++mi)
#pragma unroll
        for (int ni = 0; ni < 4; ++ni)
          acc[mi][ni] = __builtin_amdgcn_mfma_f32_16x16x32_bf16(
              aF[mi], bF[ni], acc[mi][ni], 0, 0, 0);
    }
    __syncthreads();
  }
#pragma unroll
  for (int ni = 0; ni < 4; ++ni) {
    const int col = n0 + wn + ni * 16 + l16;
    const float bb = bias[col];
#pragma unroll
    for (int mi = 0; mi < 2; ++mi) {
      const int rowb = m0 + wm + mi * 16 + kl * 4;
#pragma unroll
      for (int r = 0; r < 4; ++r) {
        const int row = rowb + r;
        if (row >= SEQ) continue;
        outp[((size_t)(col >> 7) * SEQ + row) * HD + (col & 127)] = f2b(acc[mi][ni][r] + bb);
      }
    }
  }
}

// ---------- Wo GEMM v3: 64x128, BK=64, A = head-scattered bf16, fp32 out ----------
__global__ __launch_bounds__(256) void gemm_o_k(
    const unsigned short* __restrict__ Ab, const unsigned short* __restrict__ Wt,
    const float* __restrict__ bias, float* __restrict__ outp) {
  __shared__ short As[64][72];
  __shared__ short Bs[128][72];
  const int tid = threadIdx.x;
  const int l = tid & 63, wv = tid >> 6;
  const int l16 = l & 15, kl = l >> 4;
  const int m0 = blockIdx.y * 64, n0 = blockIdx.x * 128;
  const int wm = (wv >> 1) * 32, wn = (wv & 1) * 64;
  f32x4 acc[2][4] = {};
  for (int k0 = 0; k0 < MDIM; k0 += 64) {
    {
      int m = tid >> 2, kq = tid & 3;
      int row = m0 + m, k = k0 + kq * 16;
      uint4 v0 = make_uint4(0, 0, 0, 0), v1 = make_uint4(0, 0, 0, 0);
      if (row < SEQ) {
        const unsigned short* p = Ab + ((size_t)(k >> 7) * SEQ + row) * HD + (k & 127);
        v0 = *(const uint4*)p;
        v1 = *(const uint4*)(p + 8);
      }
      *(uint4*)&As[m][kq * 16] = v0;
      *(uint4*)&As[m][kq * 16 + 8] = v1;
    }
    {
      int n = tid >> 1, kq = tid & 1;
      const unsigned short* p = Wt + (size_t)(n0 + n) * MDIM + k0 + kq * 32;
      uint4 v0 = *(const uint4*)p, v1 = *(const uint4*)(p + 8);
      uint4 v2 = *(const uint4*)(p + 16), v3 = *(const uint4*)(p + 24);
      *(uint4*)&Bs[n][kq * 32] = v0;
      *(uint4*)&Bs[n][kq * 32 + 8] = v1;
      *(uint4*)&Bs[n][kq * 32 + 16] = v2;
      *(uint4*)&Bs[n][kq * 32 + 24] = v3;
    }
    __syncthreads();
#pragma unroll
    for (int kk = 0; kk < 2; ++kk) {
      bf16x8 aF[2], bF[4];
#pragma unroll
      for (int mi = 0; mi < 2; ++mi)
        aF[mi] = *(const bf16x8*)&As[wm + mi * 16 + l16][kk * 32 + kl * 8];
#pragma unroll
      for (int ni = 0; ni < 4; ++ni)
        bF[ni] = *(const bf16x8*)&Bs[wn + ni * 16 + l16][kk * 32 + kl * 8];
#pragma unroll
      for (int mi = 0; mi < 2; ++mi)
#pragma unroll
        for (int ni = 0; ni < 4; ++ni)
          acc[mi][ni] = __builtin_amdgcn_mfma_f32_16x16x32_bf16(
              aF[mi], bF[ni], acc[mi][ni], 0, 0, 0);
    }
    __syncthreads();
  }
#pragma unroll
  for (int ni = 0; ni < 4; ++ni) {
    const int col = n0 + wn + ni * 16 + l16;
    const float bb = bias[col];
#pragma unroll
    for (int mi = 0; mi < 2; ++mi) {
      const int rowb = m0 + wm + mi * 16 + kl * 4;
#pragma unroll
      for (int r = 0; r < 4; ++r) {
        const int row = rowb + r;
        if (row >= SEQ) continue;
        outp[(size_t)row * MDIM + col] = acc[mi][ni][r] + bb;
      }
    }
  }
}

// ---------- RMSNorm + RoPE (unchanged, passing) ----------
__global__ __launch_bounds__(256) void rmsrope_k(
    unsigned short* __restrict__ Qb, unsigned short* __restrict__ Kn,
    const float* __restrict__ gq, const float* __restrict__ gk,
    const float* __restrict__ fr) {
  const int s = blockIdx.x, which = blockIdx.y;
  unsigned short* B = which ? Kn : Qb;
  const float* g = which ? gk : gq;
  __shared__ float cs[64], sn[64], red[4];
  const int t = threadIdx.x;
  if (t < 64) {
    float a = fr[s * 64 + t];
    cs[t] = cosf(a);
    sn[t] = sinf(a);
  }
  const int c0 = t * 8;
  const int hh = c0 >> 7, dd = c0 & 127, p0 = dd >> 1;
  const size_t addr = ((size_t)hh * SEQ + s) * HD + dd;
  bf16x8 v = *(const bf16x8*)(B + addr);
  float y[8];
#pragma unroll
  for (int i = 0; i < 8; ++i) y[i] = b2f((unsigned short)v[i]);
  float ssq = 0.f;
#pragma unroll
  for (int i = 0; i < 8; ++i) ssq += y[i] * y[i];
#pragma unroll
  for (int off = 32; off; off >>= 1) ssq += __shfl_xor(ssq, off);
  if ((t & 63) == 0) red[t >> 6] = ssq;
  __syncthreads();
  const float var = (red[0] + red[1] + red[2] + red[3]) * (1.0f / MDIM);
  const float rs = rsqrtf(var + 1e-6f);
  bf16x8 ov;
#pragma unroll
  for (int i = 0; i < 4; ++i) {
    float e = b2f(f2b(y[2 * i] * rs)) * g[c0 + 2 * i];
    float o = b2f(f2b(y[2 * i + 1] * rs)) * g[c0 + 2 * i + 1];
    float C = cs[p0 + i], S = sn[p0 + i];
    ov[2 * i]     = (short)f2b(e * C - o * S);
    ov[2 * i + 1] = (short)f2b(e * S + o * C);
  }
  *(bf16x8*)(B + addr) = ov;
}

// ---------- flash attention (r15-exact, ~310 us): QBLK=128, 8 waves, Pl alias Kl ----------
__global__ __launch_bounds__(512) void attn_part2_k(
    const unsigned short* __restrict__ Qb, const unsigned short* __restrict__ Kn,
    const unsigned short* __restrict__ Vn, const float* __restrict__ Kc,
    const float* __restrict__ Vc, float* __restrict__ Opart,
    float* __restrict__ ml, int chunk, int S) {
  __shared__ short UN[9216];
  __shared__ short Vt[128][72];
  const int b = blockIdx.x;
  const int xcd = b & 7;
  const int r_ = b >> 3;
  const int qt = r_ % NQT2;
  const int g = (r_ / NQT2) * 8 + xcd;
  const int h = g & (NH - 1);
  const int z = g >> 4;
  const int tid = threadIdx.x, wv = tid >> 6, l = tid & 63;
  const int l16 = l & 15, kl = l >> 4;
  const float SCALE = 0.08838834764831845f;

  const int c0 = z * chunk;
  const int cend = min(c0 + chunk, LTOT);

  int qrow = qt * 128 + wv * 16 + l16;
  if (qrow > SEQ - 1) qrow = SEQ - 1;
  bf16x8 qf[4];
#pragma unroll
  for (int kk = 0; kk < 4; ++kk)
    qf[kk] = *(const bf16x8*)(Qb + ((size_t)h * SEQ + qrow) * HD + kk * 32 + kl * 8);

  f32x4 oacc[8] = {};
  float mrow[4] = {-1e30f, -1e30f, -1e30f, -1e30f};
  float lrow[4] = {0.f, 0.f, 0.f, 0.f};

  for (int kv0 = c0; kv0 < cend; kv0 += 64) {
#pragma unroll
    for (int it = 0; it < 2; ++it) {
      int slot = tid + it * 512;
      int j = slot & 63, dq = slot >> 6;
      int jg = kv0 + j;
      U4S8 ku, vu;
      ku.u = make_uint4(0, 0, 0, 0);
      vu.u = make_uint4(0, 0, 0, 0);
      if (jg < NCACHE) {
        const float* kp = Kc + ((size_t)jg * NH + h) * HD + dq * 8;
        const float* vp = Vc + ((size_t)jg * NH + h) * HD + dq * 8;
        f32x4 ka = *(const f32x4*)(kp), kb = *(const f32x4*)(kp + 4);
        f32x4 va = *(const f32x4*)(vp), vb = *(const f32x4*)(vp + 4);
        ku.u = make_uint4(cvtpk(ka[0], ka[1]), cvtpk(ka[2], ka[3]),
                          cvtpk(kb[0], kb[1]), cvtpk(kb[2], kb[3]));
        vu.u = make_uint4(cvtpk(va[0], va[1]), cvtpk(va[2], va[3]),
                          cvtpk(vb[0], vb[1]), cvtpk(vb[2], vb[3]));
      } else if (jg < LTOT) {
        ku.u = *(const uint4*)(Kn + ((size_t)h * SEQ + (jg - NCACHE)) * HD + dq * 8);
        vu.u = *(const uint4*)(Vn + ((size_t)h * SEQ + (jg - NCACHE)) * HD + dq * 8);
      }
      *(uint4*)&UN[j * 136 + dq * 8] = ku.u;
#pragma unroll
      for (int i = 0; i < 8; ++i) Vt[dq * 8 + i][j] = vu.s[i];
    }
    __syncthreads();

    f32x4 sa[4] = {};
#pragma unroll
    for (int ni = 0; ni < 4; ++ni)
#pragma unroll
      for (int kk = 0; kk < 4; ++kk) {
        bf16x8 bK = *(const bf16x8*)&UN[(ni * 16 + l16) * 136 + kk * 32 + kl * 8];
        sa[ni] = __builtin_amdgcn_mfma_f32_16x16x32_bf16(qf[kk], bK, sa[ni], 0, 0, 0);
      }
    __syncthreads();

    float sv[4][4];
    float pm[4] = {-1e30f, -1e30f, -1e30f, -1e30f};
#pragma unroll
    for (int ni = 0; ni < 4; ++ni) {
      int jg = kv0 + ni * 16 + l16;
      bool valid = jg < LTOT;
#pragma unroll
      for (int r = 0; r < 4; ++r) {
        float xs = valid ? sa[ni][r] * SCALE : -1e30f;
        sv[ni][r] = xs;
        pm[r] = fmaxf(pm[r], xs);
      }
    }
#pragma unroll
    for (int off = 1; off < 16; off <<= 1)
#pragma unroll
      for (int r = 0; r < 4; ++r) pm[r] = fmaxf(pm[r], __shfl_xor(pm[r], off));

    float sc[4];
#pragma unroll
    for (int r = 0; r < 4; ++r) {
      float mn = fmaxf(mrow[r], pm[r]);
      sc[r] = __expf(mrow[r] - mn);
      mrow[r] = mn;
    }
    float ps[4] = {0.f, 0.f, 0.f, 0.f};
#pragma unroll
    for (int ni = 0; ni < 4; ++ni)
#pragma unroll
      for (int r = 0; r < 4; ++r) {
        float p = __expf(sv[ni][r] - mrow[r]);
        sv[ni][r] = p;
        ps[r] += p;
      }
#pragma unroll
    for (int off = 1; off < 16; off <<= 1)
#pragma unroll
      for (int r = 0; r < 4; ++r) ps[r] += __shfl_xor(ps[r], off);
#pragma unroll
    for (int r = 0; r < 4; ++r) lrow[r] = lrow[r] * sc[r] + ps[r];
#pragma unroll
    for (int di = 0; di < 8; ++di)
#pragma unroll
      for (int r = 0; r < 4; ++r) oacc[di][r] *= sc[r];
#pragma unroll
    for (int ni = 0; ni < 4; ++ni)
#pragma unroll
      for (int r = 0; r < 4; ++r)
        UN[(wv * 16 + kl * 4 + r) * 72 + ni * 16 + l16] = (short)f2b(sv[ni][r]);
    __syncthreads();

#pragma unroll
    for (int di = 0; di < 8; ++di)
#pragma unroll
      for (int k2 = 0; k2 < 2; ++k2) {
        bf16x8 aP = *(const bf16x8*)&UN[(wv * 16 + l16) * 72 + k2 * 32 + kl * 8];
        bf16x8 bV = *(const bf16x8*)&Vt[di * 16 + l16][k2 * 32 + kl * 8];
        oacc[di] = __builtin_amdgcn_mfma_f32_16x16x32_bf16(aP, bV, oacc[di], 0, 0, 0);
      }
    __syncthreads();
  }

  const size_t pbase = (((size_t)z * NH + h) * NQT2 + qt);
  const int row = wv * 16 + kl * 4;
#pragma unroll
  for (int r = 0; r < 4; ++r) {
    float* Op = Opart + (pbase * 128 + row + r) * HD;
#pragma unroll
    for (int di = 0; di < 8; ++di) Op[di * 16 + l16] = oacc[di][r];
    ml[(pbase * 2 + 0) * 128 + row + r] = mrow[r];
    ml[(pbase * 2 + 1) * 128 + row + r] = lrow[r];
  }
}

// ---------- merge partials -> bf16 O in Qb (unchanged, passing) ----------
__global__ __launch_bounds__(512) void attn_merge2_k(
    const float* __restrict__ Opart, const float* __restrict__ ml,
    unsigned short* __restrict__ Qb, int S) {
  const int qt = blockIdx.x, h = blockIdx.y;
  const int t = threadIdx.x;
  const int row = t >> 2, d0 = (t & 3) * 32;
  const int q = qt * 128 + row;

  float M = -1e30f;
  for (int s = 0; s < S; ++s) {
    const size_t pbase = (((size_t)s * NH + h) * NQT2 + qt);
    M = fmaxf(M, ml[(pbase * 2 + 0) * 128 + row]);
  }
  float L = 0.f;
  float o[32];
#pragma unroll
  for (int i = 0; i < 32; ++i) o[i] = 0.f;
  for (int s = 0; s < S; ++s) {
    const size_t pbase = (((size_t)s * NH + h) * NQT2 + qt);
    const float ms = ml[(pbase * 2 + 0) * 128 + row];
    const float ls = ml[(pbase * 2 + 1) * 128 + row];
    const float w = __expf(ms - M);
    L += w * ls;
    const float* Op = Opart + (pbase * 128 + row) * HD + d0;
#pragma unroll
    for (int c = 0; c < 8; ++c) {
      f32x4 v = *(const f32x4*)(Op + c * 4);
#pragma unroll
      for (int i = 0; i < 4; ++i) o[c * 4 + i] += w * v[i];
    }
  }
  if (q < SEQ) {
    const float inv = 1.f / L;
    unsigned short* op = Qb + ((size_t)h * SEQ + q) * HD + d0;
#pragma unroll
    for (int i = 0; i < 32; ++i) op[i] = f2b(o[i] * inv);
  }
}

extern "C" void kernel_launch(void* const* d_in, const int* in_sizes, int n_in,
                              void* d_out, int out_size, void* d_ws, size_t ws_size,
                              hipStream_t stream) {
  const float* x  = (const float*)d_in[0];
  const float* fr = (const float*)d_in[2];
  const float* Kc = (const float*)d_in[3];
  const float* Vc = (const float*)d_in[4];
  const float* Wq = (const float*)d_in[5];
  const float* bq = (const float*)d_in[6];
  const float* Wk = (const float*)d_in[7];
  const float* bk = (const float*)d_in[8];
  const float* Wv = (const float*)d_in[9];
  const float* bv = (const float*)d_in[10];
  const float* Wo = (const float*)d_in[11];
  const float* bo = (const float*)d_in[12];
  const float* gq = (const float*)d_in[13];
  const float* gk = (const float*)d_in[14];

  // ws layout: xb | Wtq Wtk Wtv Wto | Qb Kn Vn | partials
  unsigned short* xb  = (unsigned short*)d_ws;
  unsigned short* Wtq = xb + (size_t)SEQ * MDIM;            // 2,129,920 elems
  unsigned short* Wtk = Wtq + (size_t)MDIM * MDIM;
  unsigned short* Wtv = Wtk + (size_t)MDIM * MDIM;
  unsigned short* Wto = Wtv + (size_t)MDIM * MDIM;
  unsigned short* Qb  = Wto + (size_t)MDIM * MDIM;
  unsigned short* Kn  = Qb + (size_t)NH * SEQ * HD;
  unsigned short* Vn  = Kn + (size_t)NH * SEQ * HD;
  const size_t baseB = ((size_t)SEQ * MDIM + 4 * (size_t)MDIM * MDIM
                        + 3 * (size_t)NH * SEQ * HD) * 2;   // 50,593,792 B

  const size_t perSplitB = (size_t)NH * NQT2 * 128 * HD * 4
                         + (size_t)NH * NQT2 * 2 * 128 * 4;  // 9,584,640 B
  int S = 0;
  if (ws_size >= baseB + 8 * perSplitB + (1 << 20)) S = 8;
  else if (ws_size >= baseB + 6 * perSplitB + (1 << 20)) S = 6;
  else if (ws_size >= baseB + 4 * perSplitB + (1 << 19)) S = 4;  // guaranteed: ws >= 90.4 MB

  convx_k<<<dim3((SEQ * MDIM / 8 + 255) / 256), 256, 0, stream>>>(x, xb, SEQ * MDIM / 8);
  convt_k<<<dim3(32, 32, 4), 256, 0, stream>>>(Wq, Wk, Wv, Wo, Wtq, Wtk, Wtv, Wto);

  gemm_qkv_k<<<dim3(48, 17), 256, 0, stream>>>(xb, Wtq, Wtk, Wtv, bq, bk, bv, Qb, Kn, Vn);
  rmsrope_k<<<dim3(SEQ, 2), 256, 0, stream>>>(Qb, Kn, gq, gk, fr);

  float* Opart = (float*)((char*)d_ws + baseB);
  float* ml    = Opart + (size_t)S * NH * NQT2 * 128 * HD;
  const int tiles = (LTOT + 63) / 64;                        // 147
  const int chunk = ((tiles + S - 1) / S) * 64;
  attn_part2_k<<<dim3(NQT2 * NH * S), 512, 0, stream>>>(Qb, Kn, Vn, Kc, Vc, Opart, ml, chunk, S);
  attn_merge2_k<<<dim3(NQT2, NH), 512, 0, stream>>>(Opart, ml, Qb, S);

  gemm_o_k<<<dim3(16, 17), 256, 0, stream>>>(Qb, Wto, bo, (float*)d_out);
}

// Round 21
// 410.445 us; speedup vs baseline: 1.2929x; 1.0472x over previous
//
#include <hip/hip_runtime.h>

using bf16x8 = __attribute__((ext_vector_type(8))) short;
using f32x4  = __attribute__((ext_vector_type(4))) float;

#define DEV static __device__ __forceinline__

constexpr int SEQ    = 1040;
constexpr int MDIM   = 2048;
constexpr int NH     = 16;
constexpr int HD     = 128;
constexpr int NCACHE = 8320;
constexpr int LTOT   = NCACHE + SEQ;   // 9360
constexpr int KROWS  = 9408;           // padded rows for Kb/Vb (147*64)
constexpr int NQT2   = 9;              // ceil(SEQ/128)

DEV float b2f(unsigned short u) {
  union { unsigned int i; float f; } z; z.i = ((unsigned int)u) << 16; return z.f;
}
DEV unsigned short f2b(float f) {
  union { float f; unsigned int i; } z; z.f = f;
  return (unsigned short)((z.i + 0x7fffu + ((z.i >> 16) & 1u)) >> 16);
}
DEV unsigned int cvtpk(float lo, float hi) {
  unsigned int r;
  asm("v_cvt_pk_bf16_f32 %0, %1, %2" : "=v"(r) : "v"(lo), "v"(hi));
  return r;
}
union U4S8 { uint4 u; short s[8]; };

// ---------- convert x fp32 -> bf16 ----------
__global__ __launch_bounds__(256) void convx_k(
    const float* __restrict__ x, unsigned short* __restrict__ xb, int n8) {
  int i = blockIdx.x * 256 + threadIdx.x;
  if (i < n8) {
    const float* p = x + (size_t)i * 8;
    f32x4 a = *(const f32x4*)p, b = *(const f32x4*)(p + 4);
    uint4 u = make_uint4(cvtpk(a[0], a[1]), cvtpk(a[2], a[3]),
                         cvtpk(b[0], b[1]), cvtpk(b[2], b[3]));
    *(uint4*)(xb + (size_t)i * 8) = u;
  }
}

// ---------- convert KV cache fp32 -> bf16 (flat; [j][h][d] == [j][2048]) ----------
__global__ __launch_bounds__(256) void convkv_k(
    const float* __restrict__ Kc, const float* __restrict__ Vc,
    unsigned short* __restrict__ Kb, unsigned short* __restrict__ Vb, int n8) {
  int i = blockIdx.x * 256 + threadIdx.x;
  const float* src = blockIdx.y ? Vc : Kc;
  unsigned short* dst = blockIdx.y ? Vb : Kb;
  if (i < n8) {
    const float* p = src + (size_t)i * 8;
    f32x4 a = *(const f32x4*)p, b = *(const f32x4*)(p + 4);
    uint4 u = make_uint4(cvtpk(a[0], a[1]), cvtpk(a[2], a[3]),
                         cvtpk(b[0], b[1]), cvtpk(b[2], b[3]));
    *(uint4*)(dst + (size_t)i * 8) = u;
  }
}

// ---------- convert+transpose W [k][n] fp32 -> Wt [n][k] bf16 (4 weights) ----------
__global__ __launch_bounds__(256) void convt_k(
    const float* __restrict__ W0, const float* __restrict__ W1,
    const float* __restrict__ W2, const float* __restrict__ W3,
    unsigned short* __restrict__ T0, unsigned short* __restrict__ T1,
    unsigned short* __restrict__ T2, unsigned short* __restrict__ T3) {
  __shared__ short T[64][72];
  const int zz = blockIdx.z;
  const float* W = (zz == 0) ? W0 : (zz == 1) ? W1 : (zz == 2) ? W2 : W3;
  unsigned short* O = (zz == 0) ? T0 : (zz == 1) ? T1 : (zz == 2) ? T2 : T3;
  const int r0 = blockIdx.y * 64, c0 = blockIdx.x * 64;
  const int t = threadIdx.x;
  {
    int row = t >> 2, cq = t & 3;
    const float* p = W + (size_t)(r0 + row) * MDIM + c0 + cq * 16;
    f32x4 a = *(const f32x4*)(p);
    f32x4 b = *(const f32x4*)(p + 4);
    f32x4 c = *(const f32x4*)(p + 8);
    f32x4 d = *(const f32x4*)(p + 12);
    *(uint4*)&T[row][cq * 16] =
        make_uint4(cvtpk(a[0], a[1]), cvtpk(a[2], a[3]), cvtpk(b[0], b[1]), cvtpk(b[2], b[3]));
    *(uint4*)&T[row][cq * 16 + 8] =
        make_uint4(cvtpk(c[0], c[1]), cvtpk(c[2], c[3]), cvtpk(d[0], d[1]), cvtpk(d[2], d[3]));
  }
  __syncthreads();
  {
    int c = t >> 2, kq = t & 3;
    U4S8 v0, v1;
#pragma unroll
    for (int i = 0; i < 8; ++i) v0.s[i] = T[kq * 16 + i][c];
#pragma unroll
    for (int i = 0; i < 8; ++i) v1.s[i] = T[kq * 16 + 8 + i][c];
    unsigned short* op = O + (size_t)(c0 + c) * MDIM + r0 + kq * 16;
    *(uint4*)(op) = v0.u;
    *(uint4*)(op + 8) = v1.u;
  }
}

// ---------- fused QKV GEMM: 64x128, BK=64, bf16 in; Q scatter, K/V row-major tail ----------
__global__ __launch_bounds__(256) void gemm_qkv_k(
    const unsigned short* __restrict__ xb,
    const unsigned short* __restrict__ Wtq, const unsigned short* __restrict__ Wtk,
    const unsigned short* __restrict__ Wtv,
    const float* __restrict__ bq, const float* __restrict__ bk, const float* __restrict__ bv,
    unsigned short* __restrict__ Qb, unsigned short* __restrict__ Kb, unsigned short* __restrict__ Vb) {
  __shared__ short As[64][72];
  __shared__ short Bs[128][72];
  const int tid = threadIdx.x;
  const int l = tid & 63, wv = tid >> 6;
  const int l16 = l & 15, kl = l >> 4;
  const int m0 = blockIdx.y * 64;
  const int n0g = blockIdx.x * 128;
  const int which = n0g >> 11;
  const int n0 = n0g & 2047;
  const unsigned short* Wt = (which == 0) ? Wtq : (which == 1) ? Wtk : Wtv;
  const float* bias = (which == 0) ? bq : (which == 1) ? bk : bv;
  const int wm = (wv >> 1) * 32, wn = (wv & 1) * 64;
  f32x4 acc[2][4] = {};
  for (int k0 = 0; k0 < MDIM; k0 += 64) {
    {
      int m = tid >> 2, kq = tid & 3;
      int row = m0 + m;
      uint4 v0 = make_uint4(0, 0, 0, 0), v1 = make_uint4(0, 0, 0, 0);
      if (row < SEQ) {
        const unsigned short* p = xb + (size_t)row * MDIM + k0 + kq * 16;
        v0 = *(const uint4*)p;
        v1 = *(const uint4*)(p + 8);
      }
      *(uint4*)&As[m][kq * 16] = v0;
      *(uint4*)&As[m][kq * 16 + 8] = v1;
    }
    {
      int n = tid >> 1, kq = tid & 1;
      const unsigned short* p = Wt + (size_t)(n0 + n) * MDIM + k0 + kq * 32;
      uint4 v0 = *(const uint4*)p, v1 = *(const uint4*)(p + 8);
      uint4 v2 = *(const uint4*)(p + 16), v3 = *(const uint4*)(p + 24);
      *(uint4*)&Bs[n][kq * 32] = v0;
      *(uint4*)&Bs[n][kq * 32 + 8] = v1;
      *(uint4*)&Bs[n][kq * 32 + 16] = v2;
      *(uint4*)&Bs[n][kq * 32 + 24] = v3;
    }
    __syncthreads();
#pragma unroll
    for (int kk = 0; kk < 2; ++kk) {
      bf16x8 aF[2], bF[4];
#pragma unroll
      for (int mi = 0; mi < 2; ++mi)
        aF[mi] = *(const bf16x8*)&As[wm + mi * 16 + l16][kk * 32 + kl * 8];
#pragma unroll
      for (int ni = 0; ni < 4; ++ni)
        bF[ni] = *(const bf16x8*)&Bs[wn + ni * 16 + l16][kk * 32 + kl * 8];
#pragma unroll
      for (int mi = 0; mi < 2; ++mi)
#pragma unroll
        for (int ni = 0; ni < 4; ++ni)
          acc[mi][ni] = __builtin_amdgcn_mfma_f32_16x16x32_bf16(
              aF[mi], bF[ni], acc[mi][ni], 0, 0, 0);
    }
    __syncthreads();
  }
#pragma unroll
  for (int ni = 0; ni < 4; ++ni) {
    const int col = n0 + wn + ni * 16 + l16;
    const float bb = bias[col];
#pragma unroll
    for (int mi = 0; mi < 2; ++mi) {
      const int rowb = m0 + wm + mi * 16 + kl * 4;
#pragma unroll
      for (int r = 0; r < 4; ++r) {
        const int row = rowb + r;
        if (row >= SEQ) continue;
        const unsigned short val = f2b(acc[mi][ni][r] + bb);
        if (which == 0) {
          Qb[((size_t)(col >> 7) * SEQ + row) * HD + (col & 127)] = val;
        } else if (which == 1) {
          Kb[(size_t)(NCACHE + row) * MDIM + col] = val;
        } else {
          Vb[(size_t)(NCACHE + row) * MDIM + col] = val;
        }
      }
    }
  }
}

// ---------- Wo GEMM: 64x128, BK=64, A head-scattered bf16, fp32 out (r20, passing) ----------
__global__ __launch_bounds__(256) void gemm_o_k(
    const unsigned short* __restrict__ Ab, const unsigned short* __restrict__ Wt,
    const float* __restrict__ bias, float* __restrict__ outp) {
  __shared__ short As[64][72];
  __shared__ short Bs[128][72];
  const int tid = threadIdx.x;
  const int l = tid & 63, wv = tid >> 6;
  const int l16 = l & 15, kl = l >> 4;
  const int m0 = blockIdx.y * 64, n0 = blockIdx.x * 128;
  const int wm = (wv >> 1) * 32, wn = (wv & 1) * 64;
  f32x4 acc[2][4] = {};
  for (int k0 = 0; k0 < MDIM; k0 += 64) {
    {
      int m = tid >> 2, kq = tid & 3;
      int row = m0 + m, k = k0 + kq * 16;
      uint4 v0 = make_uint4(0, 0, 0, 0), v1 = make_uint4(0, 0, 0, 0);
      if (row < SEQ) {
        const unsigned short* p = Ab + ((size_t)(k >> 7) * SEQ + row) * HD + (k & 127);
        v0 = *(const uint4*)p;
        v1 = *(const uint4*)(p + 8);
      }
      *(uint4*)&As[m][kq * 16] = v0;
      *(uint4*)&As[m][kq * 16 + 8] = v1;
    }
    {
      int n = tid >> 1, kq = tid & 1;
      const unsigned short* p = Wt + (size_t)(n0 + n) * MDIM + k0 + kq * 32;
      uint4 v0 = *(const uint4*)p, v1 = *(const uint4*)(p + 8);
      uint4 v2 = *(const uint4*)(p + 16), v3 = *(const uint4*)(p + 24);
      *(uint4*)&Bs[n][kq * 32] = v0;
      *(uint4*)&Bs[n][kq * 32 + 8] = v1;
      *(uint4*)&Bs[n][kq * 32 + 16] = v2;
      *(uint4*)&Bs[n][kq * 32 + 24] = v3;
    }
    __syncthreads();
#pragma unroll
    for (int kk = 0; kk < 2; ++kk) {
      bf16x8 aF[2], bF[4];
#pragma unroll
      for (int mi = 0; mi < 2; ++mi)
        aF[mi] = *(const bf16x8*)&As[wm + mi * 16 + l16][kk * 32 + kl * 8];
#pragma unroll
      for (int ni = 0; ni < 4; ++ni)
        bF[ni] = *(const bf16x8*)&Bs[wn + ni * 16 + l16][kk * 32 + kl * 8];
#pragma unroll
      for (int mi = 0; mi < 2; ++mi)
#pragma unroll
        for (int ni = 0; ni < 4; ++ni)
          acc[mi][ni] = __builtin_amdgcn_mfma_f32_16x16x32_bf16(
              aF[mi], bF[ni], acc[mi][ni], 0, 0, 0);
    }
    __syncthreads();
  }
#pragma unroll
  for (int ni = 0; ni < 4; ++ni) {
    const int col = n0 + wn + ni * 16 + l16;
    const float bb = bias[col];
#pragma unroll
    for (int mi = 0; mi < 2; ++mi) {
      const int rowb = m0 + wm + mi * 16 + kl * 4;
#pragma unroll
      for (int r = 0; r < 4; ++r) {
        const int row = rowb + r;
        if (row >= SEQ) continue;
        outp[(size_t)row * MDIM + col] = acc[mi][ni][r] + bb;
      }
    }
  }
}

// ---------- RMSNorm + RoPE: y==0 Q (scatter layout), y==1 K (row-major Kb tail) ----------
__global__ __launch_bounds__(256) void rmsrope_k(
    unsigned short* __restrict__ Qb, unsigned short* __restrict__ Kb,
    const float* __restrict__ gq, const float* __restrict__ gk,
    const float* __restrict__ fr) {
  const int s = blockIdx.x, which = blockIdx.y;
  const float* g = which ? gk : gq;
  __shared__ float cs[64], sn[64], red[4];
  const int t = threadIdx.x;
  if (t < 64) {
    float a = fr[s * 64 + t];
    cs[t] = cosf(a);
    sn[t] = sinf(a);
  }
  const int c0 = t * 8;
  const int hh = c0 >> 7, dd = c0 & 127, p0 = dd >> 1;
  unsigned short* ptr = which
      ? Kb + (size_t)(NCACHE + s) * MDIM + c0
      : Qb + ((size_t)hh * SEQ + s) * HD + dd;
  bf16x8 v = *(const bf16x8*)ptr;
  float y[8];
#pragma unroll
  for (int i = 0; i < 8; ++i) y[i] = b2f((unsigned short)v[i]);
  float ssq = 0.f;
#pragma unroll
  for (int i = 0; i < 8; ++i) ssq += y[i] * y[i];
#pragma unroll
  for (int off = 32; off; off >>= 1) ssq += __shfl_xor(ssq, off);
  if ((t & 63) == 0) red[t >> 6] = ssq;
  __syncthreads();
  const float var = (red[0] + red[1] + red[2] + red[3]) * (1.0f / MDIM);
  const float rs = rsqrtf(var + 1e-6f);
  bf16x8 ov;
#pragma unroll
  for (int i = 0; i < 4; ++i) {
    float e = b2f(f2b(y[2 * i] * rs)) * g[c0 + 2 * i];
    float o = b2f(f2b(y[2 * i + 1] * rs)) * g[c0 + 2 * i + 1];
    float C = cs[p0 + i], S = sn[p0 + i];
    ov[2 * i]     = (short)f2b(e * C - o * S);
    ov[2 * i + 1] = (short)f2b(e * S + o * C);
  }
  *(bf16x8*)ptr = ov;
}

// ---------- flash attention v6: unified bf16 KV [row][2048]; pure uint4 staging ----------
__global__ __launch_bounds__(512) void attn_part6_k(
    const unsigned short* __restrict__ Qb, const unsigned short* __restrict__ Kb,
    const unsigned short* __restrict__ Vb, unsigned short* __restrict__ Opart,
    float* __restrict__ ml, int chunk, int S) {
  __shared__ short UN[9216];        // Kl: UN[j*136+d]; Pl: UN[(w*16+r)*72+c] (aliased)
  __shared__ short Vt[128][72];
  const int b = blockIdx.x;
  const int xcd = b & 7;
  const int r_ = b >> 3;
  const int qt = r_ % NQT2;
  const int g = (r_ / NQT2) * 8 + xcd;
  const int h = g & (NH - 1);
  const int z = g >> 4;
  const int tid = threadIdx.x, wv = tid >> 6, l = tid & 63;
  const int l16 = l & 15, kl = l >> 4;
  const float SCALE = 0.08838834764831845f;

  const int c0 = z * chunk;
  const int cend = min(c0 + chunk, LTOT);

  int qrow = qt * 128 + wv * 16 + l16;
  if (qrow > SEQ - 1) qrow = SEQ - 1;
  bf16x8 qf[4];
#pragma unroll
  for (int kk = 0; kk < 4; ++kk)
    qf[kk] = *(const bf16x8*)(Qb + ((size_t)h * SEQ + qrow) * HD + kk * 32 + kl * 8);

  f32x4 oacc[8] = {};
  float mrow[4] = {-1e30f, -1e30f, -1e30f, -1e30f};
  float lrow[4] = {0.f, 0.f, 0.f, 0.f};

  const int j0 = tid & 63, dq0 = tid >> 6, dq1 = (tid + 512) >> 6;
  const int hofs = h * HD;

  for (int kv0 = c0; kv0 < cend; kv0 += 64) {
    const size_t rbase = (size_t)(kv0 + j0) * MDIM + hofs;
#pragma unroll
    for (int it = 0; it < 2; ++it) {
      const int dq = (it == 0) ? dq0 : dq1;
      uint4 ku = *(const uint4*)(Kb + rbase + dq * 8);
      U4S8 vu; vu.u = *(const uint4*)(Vb + rbase + dq * 8);
      *(uint4*)&UN[j0 * 136 + dq * 8] = ku;
#pragma unroll
      for (int i = 0; i < 8; ++i) Vt[dq * 8 + i][j0] = vu.s[i];
    }
    __syncthreads();                                   // bar1: K/V staged

    f32x4 sa[4] = {};
#pragma unroll
    for (int ni = 0; ni < 4; ++ni)
#pragma unroll
      for (int kk = 0; kk < 4; ++kk) {
        bf16x8 bK = *(const bf16x8*)&UN[(ni * 16 + l16) * 136 + kk * 32 + kl * 8];
        sa[ni] = __builtin_amdgcn_mfma_f32_16x16x32_bf16(qf[kk], bK, sa[ni], 0, 0, 0);
      }
    __syncthreads();                                   // bar2: QK reads done (Pl aliases Kl)

    float sv[4][4];
    float pm[4] = {-1e30f, -1e30f, -1e30f, -1e30f};
#pragma unroll
    for (int ni = 0; ni < 4; ++ni) {
      int jg = kv0 + ni * 16 + l16;
      bool valid = jg < LTOT;
#pragma unroll
      for (int r = 0; r < 4; ++r) {
        float xs = valid ? sa[ni][r] * SCALE : -1e30f;
        sv[ni][r] = xs;
        pm[r] = fmaxf(pm[r], xs);
      }
    }
#pragma unroll
    for (int off = 1; off < 16; off <<= 1)
#pragma unroll
      for (int r = 0; r < 4; ++r) pm[r] = fmaxf(pm[r], __shfl_xor(pm[r], off));

    float sc[4];
#pragma unroll
    for (int r = 0; r < 4; ++r) {
      float mn = fmaxf(mrow[r], pm[r]);
      sc[r] = __expf(mrow[r] - mn);
      mrow[r] = mn;
    }
    float ps[4] = {0.f, 0.f, 0.f, 0.f};
#pragma unroll
    for (int ni = 0; ni < 4; ++ni)
#pragma unroll
      for (int r = 0; r < 4; ++r) {
        float p = __expf(sv[ni][r] - mrow[r]);
        sv[ni][r] = p;
        ps[r] += p;
      }
#pragma unroll
    for (int off = 1; off < 16; off <<= 1)
#pragma unroll
      for (int r = 0; r < 4; ++r) ps[r] += __shfl_xor(ps[r], off);
#pragma unroll
    for (int r = 0; r < 4; ++r) lrow[r] = lrow[r] * sc[r] + ps[r];
#pragma unroll
    for (int di = 0; di < 8; ++di)
#pragma unroll
      for (int r = 0; r < 4; ++r) oacc[di][r] *= sc[r];
#pragma unroll
    for (int ni = 0; ni < 4; ++ni)
#pragma unroll
      for (int r = 0; r < 4; ++r)
        UN[(wv * 16 + kl * 4 + r) * 72 + ni * 16 + l16] = (short)f2b(sv[ni][r]);
    __syncthreads();                                   // bar3: P staged

#pragma unroll
    for (int di = 0; di < 8; ++di)
#pragma unroll
      for (int k2 = 0; k2 < 2; ++k2) {
        bf16x8 aP = *(const bf16x8*)&UN[(wv * 16 + l16) * 72 + k2 * 32 + kl * 8];
        bf16x8 bV = *(const bf16x8*)&Vt[di * 16 + l16][k2 * 32 + kl * 8];
        oacc[di] = __builtin_amdgcn_mfma_f32_16x16x32_bf16(aP, bV, oacc[di], 0, 0, 0);
      }
    __syncthreads();                                   // bar4
  }

  const size_t pbase = (((size_t)z * NH + h) * NQT2 + qt);
  const int row = wv * 16 + kl * 4;
#pragma unroll
  for (int r = 0; r < 4; ++r) {
    unsigned short* Op = Opart + (pbase * 128 + row + r) * HD;
#pragma unroll
    for (int di = 0; di < 8; ++di) Op[di * 16 + l16] = f2b(oacc[di][r]);
    ml[(pbase * 2 + 0) * 128 + row + r] = mrow[r];
    ml[(pbase * 2 + 1) * 128 + row + r] = lrow[r];
  }
}

// ---------- merge bf16 partials -> bf16 O in Qb ----------
__global__ __launch_bounds__(512) void attn_merge3_k(
    const unsigned short* __restrict__ Opart, const float* __restrict__ ml,
    unsigned short* __restrict__ Qb, int S) {
  const int qt = blockIdx.x, h = blockIdx.y;
  const int t = threadIdx.x;
  const int row = t >> 2, d0 = (t & 3) * 32;
  const int q = qt * 128 + row;

  float M = -1e30f;
  for (int s = 0; s < S; ++s) {
    const size_t pbase = (((size_t)s * NH + h) * NQT2 + qt);
    M = fmaxf(M, ml[(pbase * 2 + 0) * 128 + row]);
  }
  float L = 0.f;
  float o[32];
#pragma unroll
  for (int i = 0; i < 32; ++i) o[i] = 0.f;
  for (int s = 0; s < S; ++s) {
    const size_t pbase = (((size_t)s * NH + h) * NQT2 + qt);
    const float ms = ml[(pbase * 2 + 0) * 128 + row];
    const float ls = ml[(pbase * 2 + 1) * 128 + row];
    const float w = __expf(ms - M);
    L += w * ls;
    const unsigned short* Op = Opart + (pbase * 128 + row) * HD + d0;
#pragma unroll
    for (int c = 0; c < 4; ++c) {
      bf16x8 v = *(const bf16x8*)(Op + c * 8);
#pragma unroll
      for (int i = 0; i < 8; ++i) o[c * 8 + i] += w * b2f((unsigned short)v[i]);
    }
  }
  if (q < SEQ) {
    const float inv = 1.f / L;
    unsigned short* op = Qb + ((size_t)h * SEQ + q) * HD + d0;
#pragma unroll
    for (int i = 0; i < 32; ++i) op[i] = f2b(o[i] * inv);
  }
}

extern "C" void kernel_launch(void* const* d_in, const int* in_sizes, int n_in,
                              void* d_out, int out_size, void* d_ws, size_t ws_size,
                              hipStream_t stream) {
  const float* x  = (const float*)d_in[0];
  const float* fr = (const float*)d_in[2];
  const float* Kc = (const float*)d_in[3];
  const float* Vc = (const float*)d_in[4];
  const float* Wq = (const float*)d_in[5];
  const float* bq = (const float*)d_in[6];
  const float* Wk = (const float*)d_in[7];
  const float* bk = (const float*)d_in[8];
  const float* Wv = (const float*)d_in[9];
  const float* bv = (const float*)d_in[10];
  const float* Wo = (const float*)d_in[11];
  const float* bo = (const float*)d_in[12];
  const float* gq = (const float*)d_in[13];
  const float* gk = (const float*)d_in[14];

  // ws: xb | Wto | Qb | Kb | Vb | [Wtq Wtk Wtv == partial-alias zone] | extra
  unsigned short* xb  = (unsigned short*)d_ws;
  unsigned short* Wto = xb + (size_t)SEQ * MDIM;
  unsigned short* Qb  = Wto + (size_t)MDIM * MDIM;
  unsigned short* Kb  = Qb + (size_t)NH * SEQ * HD;
  unsigned short* Vb  = Kb + (size_t)KROWS * MDIM;
  unsigned short* Wtq = Vb + (size_t)KROWS * MDIM;
  unsigned short* Wtk = Wtq + (size_t)MDIM * MDIM;
  unsigned short* Wtv = Wtk + (size_t)MDIM * MDIM;
  const size_t fixedB = ((size_t)SEQ * MDIM + (size_t)MDIM * MDIM + (size_t)NH * SEQ * HD
                         + 2 * (size_t)KROWS * MDIM) * 2;          // 93.99 MB
  const size_t aliasB = 3 * (size_t)MDIM * MDIM * 2;               // 25.17 MB

  // partials (Opart bf16 + ml fp32) per split:
  const size_t perSplitB = (size_t)NH * NQT2 * 128 * HD * 2
                         + (size_t)NH * NQT2 * 2 * 128 * 4;        // 4.87 MB
  int S = 4;                                                        // guaranteed fit in alias zone
  if (ws_size >= fixedB + aliasB + (8 * perSplitB - aliasB) + (1 << 21)) S = 8;

  unsigned short* Opart = Wtq;                                      // aliases dead Wt zone
  float* ml = (float*)((char*)Wtq + (size_t)S * NH * NQT2 * 128 * HD * 2);

  const int n8x = SEQ * MDIM / 8;
  const int n8kv = NCACHE * MDIM / 8;
  convx_k<<<dim3((n8x + 255) / 256), 256, 0, stream>>>(x, xb, n8x);
  convkv_k<<<dim3((n8kv + 255) / 256, 2), 256, 0, stream>>>(Kc, Vc, Kb, Vb, n8kv);
  convt_k<<<dim3(32, 32, 4), 256, 0, stream>>>(Wq, Wk, Wv, Wo, Wtq, Wtk, Wtv, Wto);

  gemm_qkv_k<<<dim3(48, 17), 256, 0, stream>>>(xb, Wtq, Wtk, Wtv, bq, bk, bv, Qb, Kb, Vb);
  rmsrope_k<<<dim3(SEQ, 2), 256, 0, stream>>>(Qb, Kb, gq, gk, fr);

  const int tiles = (LTOT + 63) / 64;                               // 147
  const int chunk = ((tiles + S - 1) / S) * 64;
  attn_part6_k<<<dim3(NQT2 * NH * S), 512, 0, stream>>>(Qb, Kb, Vb, Opart, ml, chunk, S);
  attn_merge3_k<<<dim3(NQT2, NH), 512, 0, stream>>>(Opart, ml, Qb, S);

  gemm_o_k<<<dim3(16, 17), 256, 0, stream>>>(Qb, Wto, bo, (float*)d_out);
}

// Round 22
// 405.392 us; speedup vs baseline: 1.3090x; 1.0125x over previous
//
#include <hip/hip_runtime.h>

using bf16x8 = __attribute__((ext_vector_type(8))) short;
using f32x4  = __attribute__((ext_vector_type(4))) float;

#define DEV static __device__ __forceinline__

constexpr int SEQ    = 1040;
constexpr int MDIM   = 2048;
constexpr int NH     = 16;
constexpr int HD     = 128;
constexpr int NCACHE = 8320;
constexpr int LTOT   = NCACHE + SEQ;   // 9360
constexpr int NTILE  = 147;            // ceil(LTOT/64)
constexpr int KROWS  = NTILE * 64;     // 9408
constexpr int NQT2   = 9;              // ceil(SEQ/128)
constexpr int SPLITS = 6;              // 16*6 groups % 8 == 0; 864 blocks; 25 tiles/block

DEV float b2f(unsigned short u) {
  union { unsigned int i; float f; } z; z.i = ((unsigned int)u) << 16; return z.f;
}
DEV unsigned short f2b(float f) {
  union { float f; unsigned int i; } z; z.f = f;
  return (unsigned short)((z.i + 0x7fffu + ((z.i >> 16) & 1u)) >> 16);
}
DEV unsigned int cvtpk(float lo, float hi) {
  unsigned int r;
  asm("v_cvt_pk_bf16_f32 %0, %1, %2" : "=v"(r) : "v"(lo), "v"(hi));
  return r;
}
union U4S8 { uint4 u; short s[8]; };

// ---------- convert x fp32 -> bf16 ----------
__global__ __launch_bounds__(256) void convx_k(
    const float* __restrict__ x, unsigned short* __restrict__ xb, int n8) {
  int i = blockIdx.x * 256 + threadIdx.x;
  if (i < n8) {
    const float* p = x + (size_t)i * 8;
    f32x4 a = *(const f32x4*)p, b = *(const f32x4*)(p + 4);
    uint4 u = make_uint4(cvtpk(a[0], a[1]), cvtpk(a[2], a[3]),
                         cvtpk(b[0], b[1]), cvtpk(b[2], b[3]));
    *(uint4*)(xb + (size_t)i * 8) = u;
  }
}

// ---------- K cache fp32 -> bf16 flat ----------
__global__ __launch_bounds__(256) void convk_k(
    const float* __restrict__ Kc, unsigned short* __restrict__ Kb, int n8) {
  int i = blockIdx.x * 256 + threadIdx.x;
  if (i < n8) {
    const float* p = Kc + (size_t)i * 8;
    f32x4 a = *(const f32x4*)p, b = *(const f32x4*)(p + 4);
    uint4 u = make_uint4(cvtpk(a[0], a[1]), cvtpk(a[2], a[3]),
                         cvtpk(b[0], b[1]), cvtpk(b[2], b[3]));
    *(uint4*)(Kb + (size_t)i * 8) = u;
  }
}

// ---------- V cache fp32 -> bf16 pre-transposed Vbt[tile][h][d][j] ----------
// grid (130, 16): cache tiles x heads
__global__ __launch_bounds__(256) void convvt_k(
    const float* __restrict__ Vc, unsigned short* __restrict__ Vbt) {
  __shared__ short T[64][136];
  const int tile = blockIdx.x, h = blockIdx.y;
  const int t = threadIdx.x;
  {
    int row = t >> 2, cq = t & 3;
    const float* p = Vc + (size_t)(tile * 64 + row) * MDIM + h * HD + cq * 32;
#pragma unroll
    for (int k = 0; k < 4; ++k) {
      f32x4 a = *(const f32x4*)(p + k * 8);
      f32x4 b = *(const f32x4*)(p + k * 8 + 4);
      *(uint4*)&T[row][cq * 32 + k * 8] =
          make_uint4(cvtpk(a[0], a[1]), cvtpk(a[2], a[3]), cvtpk(b[0], b[1]), cvtpk(b[2], b[3]));
    }
  }
  __syncthreads();
#pragma unroll
  for (int i = 0; i < 4; ++i) {
    int c = t + i * 256;
    int d = c >> 3, joct = c & 7;
    U4S8 u;
#pragma unroll
    for (int jj = 0; jj < 8; ++jj) u.s[jj] = T[joct * 8 + jj][d];
    *(uint4*)(Vbt + ((((size_t)tile * NH + h) * HD + d) * 64 + joct * 8)) = u.u;
  }
}

// ---------- convert+transpose W [k][n] fp32 -> Wt [n][k] bf16 (4 weights) ----------
__global__ __launch_bounds__(256) void convt_k(
    const float* __restrict__ W0, const float* __restrict__ W1,
    const float* __restrict__ W2, const float* __restrict__ W3,
    unsigned short* __restrict__ T0, unsigned short* __restrict__ T1,
    unsigned short* __restrict__ T2, unsigned short* __restrict__ T3) {
  __shared__ short T[64][72];
  const int zz = blockIdx.z;
  const float* W = (zz == 0) ? W0 : (zz == 1) ? W1 : (zz == 2) ? W2 : W3;
  unsigned short* O = (zz == 0) ? T0 : (zz == 1) ? T1 : (zz == 2) ? T2 : T3;
  const int r0 = blockIdx.y * 64, c0 = blockIdx.x * 64;
  const int t = threadIdx.x;
  {
    int row = t >> 2, cq = t & 3;
    const float* p = W + (size_t)(r0 + row) * MDIM + c0 + cq * 16;
    f32x4 a = *(const f32x4*)(p);
    f32x4 b = *(const f32x4*)(p + 4);
    f32x4 c = *(const f32x4*)(p + 8);
    f32x4 d = *(const f32x4*)(p + 12);
    *(uint4*)&T[row][cq * 16] =
        make_uint4(cvtpk(a[0], a[1]), cvtpk(a[2], a[3]), cvtpk(b[0], b[1]), cvtpk(b[2], b[3]));
    *(uint4*)&T[row][cq * 16 + 8] =
        make_uint4(cvtpk(c[0], c[1]), cvtpk(c[2], c[3]), cvtpk(d[0], d[1]), cvtpk(d[2], d[3]));
  }
  __syncthreads();
  {
    int c = t >> 2, kq = t & 3;
    U4S8 v0, v1;
#pragma unroll
    for (int i = 0; i < 8; ++i) v0.s[i] = T[kq * 16 + i][c];
#pragma unroll
    for (int i = 0; i < 8; ++i) v1.s[i] = T[kq * 16 + 8 + i][c];
    unsigned short* op = O + (size_t)(c0 + c) * MDIM + r0 + kq * 16;
    *(uint4*)(op) = v0.u;
    *(uint4*)(op + 8) = v1.u;
  }
}

// ---------- fused QKV GEMM: Q scatter, K row-major tail, V transposed-scatter ----------
__global__ __launch_bounds__(256) void gemm_qkv_k(
    const unsigned short* __restrict__ xb,
    const unsigned short* __restrict__ Wtq, const unsigned short* __restrict__ Wtk,
    const unsigned short* __restrict__ Wtv,
    const float* __restrict__ bq, const float* __restrict__ bk, const float* __restrict__ bv,
    unsigned short* __restrict__ Qb, unsigned short* __restrict__ Kb, unsigned short* __restrict__ Vbt) {
  __shared__ short As[64][72];
  __shared__ short Bs[128][72];
  const int tid = threadIdx.x;
  const int l = tid & 63, wv = tid >> 6;
  const int l16 = l & 15, kl = l >> 4;
  const int m0 = blockIdx.y * 64;
  const int n0g = blockIdx.x * 128;
  const int which = n0g >> 11;
  const int n0 = n0g & 2047;
  const unsigned short* Wt = (which == 0) ? Wtq : (which == 1) ? Wtk : Wtv;
  const float* bias = (which == 0) ? bq : (which == 1) ? bk : bv;
  const int wm = (wv >> 1) * 32, wn = (wv & 1) * 64;
  f32x4 acc[2][4] = {};
  for (int k0 = 0; k0 < MDIM; k0 += 64) {
    {
      int m = tid >> 2, kq = tid & 3;
      int row = m0 + m;
      uint4 v0 = make_uint4(0, 0, 0, 0), v1 = make_uint4(0, 0, 0, 0);
      if (row < SEQ) {
        const unsigned short* p = xb + (size_t)row * MDIM + k0 + kq * 16;
        v0 = *(const uint4*)p;
        v1 = *(const uint4*)(p + 8);
      }
      *(uint4*)&As[m][kq * 16] = v0;
      *(uint4*)&As[m][kq * 16 + 8] = v1;
    }
    {
      int n = tid >> 1, kq = tid & 1;
      const unsigned short* p = Wt + (size_t)(n0 + n) * MDIM + k0 + kq * 32;
      uint4 v0 = *(const uint4*)p, v1 = *(const uint4*)(p + 8);
      uint4 v2 = *(const uint4*)(p + 16), v3 = *(const uint4*)(p + 24);
      *(uint4*)&Bs[n][kq * 32] = v0;
      *(uint4*)&Bs[n][kq * 32 + 8] = v1;
      *(uint4*)&Bs[n][kq * 32 + 16] = v2;
      *(uint4*)&Bs[n][kq * 32 + 24] = v3;
    }
    __syncthreads();
#pragma unroll
    for (int kk = 0; kk < 2; ++kk) {
      bf16x8 aF[2], bF[4];
#pragma unroll
      for (int mi = 0; mi < 2; ++mi)
        aF[mi] = *(const bf16x8*)&As[wm + mi * 16 + l16][kk * 32 + kl * 8];
#pragma unroll
      for (int ni = 0; ni < 4; ++ni)
        bF[ni] = *(const bf16x8*)&Bs[wn + ni * 16 + l16][kk * 32 + kl * 8];
#pragma unroll
      for (int mi = 0; mi < 2; ++mi)
#pragma unroll
        for (int ni = 0; ni < 4; ++ni)
          acc[mi][ni] = __builtin_amdgcn_mfma_f32_16x16x32_bf16(
              aF[mi], bF[ni], acc[mi][ni], 0, 0, 0);
    }
    __syncthreads();
  }
#pragma unroll
  for (int ni = 0; ni < 4; ++ni) {
    const int col = n0 + wn + ni * 16 + l16;
    const float bb = bias[col];
    const int hh = col >> 7, dd = col & 127;
#pragma unroll
    for (int mi = 0; mi < 2; ++mi) {
      const int rowb = m0 + wm + mi * 16 + kl * 4;
#pragma unroll
      for (int r = 0; r < 4; ++r) {
        const int row = rowb + r;
        if (row >= SEQ) continue;
        const unsigned short val = f2b(acc[mi][ni][r] + bb);
        if (which == 0) {
          Qb[((size_t)hh * SEQ + row) * HD + dd] = val;
        } else if (which == 1) {
          Kb[(size_t)(NCACHE + row) * MDIM + col] = val;
        } else {
          const int g = NCACHE + row;
          Vbt[(((size_t)(g >> 6) * NH + hh) * HD + dd) * 64 + (g & 63)] = val;
        }
      }
    }
  }
}

// ---------- Wo GEMM (r20, passing) ----------
__global__ __launch_bounds__(256) void gemm_o_k(
    const unsigned short* __restrict__ Ab, const unsigned short* __restrict__ Wt,
    const float* __restrict__ bias, float* __restrict__ outp) {
  __shared__ short As[64][72];
  __shared__ short Bs[128][72];
  const int tid = threadIdx.x;
  const int l = tid & 63, wv = tid >> 6;
  const int l16 = l & 15, kl = l >> 4;
  const int m0 = blockIdx.y * 64, n0 = blockIdx.x * 128;
  const int wm = (wv >> 1) * 32, wn = (wv & 1) * 64;
  f32x4 acc[2][4] = {};
  for (int k0 = 0; k0 < MDIM; k0 += 64) {
    {
      int m = tid >> 2, kq = tid & 3;
      int row = m0 + m, k = k0 + kq * 16;
      uint4 v0 = make_uint4(0, 0, 0, 0), v1 = make_uint4(0, 0, 0, 0);
      if (row < SEQ) {
        const unsigned short* p = Ab + ((size_t)(k >> 7) * SEQ + row) * HD + (k & 127);
        v0 = *(const uint4*)p;
        v1 = *(const uint4*)(p + 8);
      }
      *(uint4*)&As[m][kq * 16] = v0;
      *(uint4*)&As[m][kq * 16 + 8] = v1;
    }
    {
      int n = tid >> 1, kq = tid & 1;
      const unsigned short* p = Wt + (size_t)(n0 + n) * MDIM + k0 + kq * 32;
      uint4 v0 = *(const uint4*)p, v1 = *(const uint4*)(p + 8);
      uint4 v2 = *(const uint4*)(p + 16), v3 = *(const uint4*)(p + 24);
      *(uint4*)&Bs[n][kq * 32] = v0;
      *(uint4*)&Bs[n][kq * 32 + 8] = v1;
      *(uint4*)&Bs[n][kq * 32 + 16] = v2;
      *(uint4*)&Bs[n][kq * 32 + 24] = v3;
    }
    __syncthreads();
#pragma unroll
    for (int kk = 0; kk < 2; ++kk) {
      bf16x8 aF[2], bF[4];
#pragma unroll
      for (int mi = 0; mi < 2; ++mi)
        aF[mi] = *(const bf16x8*)&As[wm + mi * 16 + l16][kk * 32 + kl * 8];
#pragma unroll
      for (int ni = 0; ni < 4; ++ni)
        bF[ni] = *(const bf16x8*)&Bs[wn + ni * 16 + l16][kk * 32 + kl * 8];
#pragma unroll
      for (int mi = 0; mi < 2; ++mi)
#pragma unroll
        for (int ni = 0; ni < 4; ++ni)
          acc[mi][ni] = __builtin_amdgcn_mfma_f32_16x16x32_bf16(
              aF[mi], bF[ni], acc[mi][ni], 0, 0, 0);
    }
    __syncthreads();
  }
#pragma unroll
  for (int ni = 0; ni < 4; ++ni) {
    const int col = n0 + wn + ni * 16 + l16;
    const float bb = bias[col];
#pragma unroll
    for (int mi = 0; mi < 2; ++mi) {
      const int rowb = m0 + wm + mi * 16 + kl * 4;
#pragma unroll
      for (int r = 0; r < 4; ++r) {
        const int row = rowb + r;
        if (row >= SEQ) continue;
        outp[(size_t)row * MDIM + col] = acc[mi][ni][r] + bb;
      }
    }
  }
}

// ---------- RMSNorm + RoPE: y==0 Q (scatter), y==1 K (Kb tail row-major) ----------
__global__ __launch_bounds__(256) void rmsrope_k(
    unsigned short* __restrict__ Qb, unsigned short* __restrict__ Kb,
    const float* __restrict__ gq, const float* __restrict__ gk,
    const float* __restrict__ fr) {
  const int s = blockIdx.x, which = blockIdx.y;
  const float* g = which ? gk : gq;
  __shared__ float cs[64], sn[64], red[4];
  const int t = threadIdx.x;
  if (t < 64) {
    float a = fr[s * 64 + t];
    cs[t] = cosf(a);
    sn[t] = sinf(a);
  }
  const int c0 = t * 8;
  const int hh = c0 >> 7, dd = c0 & 127, p0 = dd >> 1;
  unsigned short* ptr = which
      ? Kb + (size_t)(NCACHE + s) * MDIM + c0
      : Qb + ((size_t)hh * SEQ + s) * HD + dd;
  bf16x8 v = *(const bf16x8*)ptr;
  float y[8];
#pragma unroll
  for (int i = 0; i < 8; ++i) y[i] = b2f((unsigned short)v[i]);
  float ssq = 0.f;
#pragma unroll
  for (int i = 0; i < 8; ++i) ssq += y[i] * y[i];
#pragma unroll
  for (int off = 32; off; off >>= 1) ssq += __shfl_xor(ssq, off);
  if ((t & 63) == 0) red[t >> 6] = ssq;
  __syncthreads();
  const float var = (red[0] + red[1] + red[2] + red[3]) * (1.0f / MDIM);
  const float rs = rsqrtf(var + 1e-6f);
  bf16x8 ov;
#pragma unroll
  for (int i = 0; i < 4; ++i) {
    float e = b2f(f2b(y[2 * i] * rs)) * g[c0 + 2 * i];
    float o = b2f(f2b(y[2 * i + 1] * rs)) * g[c0 + 2 * i + 1];
    float C = cs[p0 + i], S = sn[p0 + i];
    ov[2 * i]     = (short)f2b(e * C - o * S);
    ov[2 * i + 1] = (short)f2b(e * S + o * C);
  }
  *(bf16x8*)ptr = ov;
}

// ---------- flash attention v7: bf16 K row-major + V pre-transposed; pure uint4 staging ----------
__global__ __launch_bounds__(512) void attn_part7_k(
    const unsigned short* __restrict__ Qb, const unsigned short* __restrict__ Kb,
    const unsigned short* __restrict__ Vbt, unsigned short* __restrict__ Opart,
    float* __restrict__ ml, int chunk, int S) {
  __shared__ short UN[9216];        // Kl: UN[j*136+d]; Pl: UN[(w*16+r)*72+c] (aliased)
  __shared__ short Vt[128][72];
  const int b = blockIdx.x;
  const int xcd = b & 7;
  const int r_ = b >> 3;
  const int qt = r_ % NQT2;
  const int g = (r_ / NQT2) * 8 + xcd;
  const int h = g & (NH - 1);
  const int z = g >> 4;
  const int tid = threadIdx.x, wv = tid >> 6, l = tid & 63;
  const int l16 = l & 15, kl = l >> 4;
  const float SCALE = 0.08838834764831845f;

  const int c0 = z * chunk;
  const int cend = min(c0 + chunk, LTOT);

  int qrow = qt * 128 + wv * 16 + l16;
  if (qrow > SEQ - 1) qrow = SEQ - 1;
  bf16x8 qf[4];
#pragma unroll
  for (int kk = 0; kk < 4; ++kk)
    qf[kk] = *(const bf16x8*)(Qb + ((size_t)h * SEQ + qrow) * HD + kk * 32 + kl * 8);

  f32x4 oacc[8] = {};
  float mrow[4] = {-1e30f, -1e30f, -1e30f, -1e30f};
  float lrow[4] = {0.f, 0.f, 0.f, 0.f};

  const int j0 = tid & 63, dq0 = tid >> 6, dq1 = (tid + 512) >> 6;
  const int dV0 = tid >> 3, dV1 = (tid + 512) >> 3, jo = tid & 7;
  const int hofs = h * HD;

  for (int kv0 = c0; kv0 < cend; kv0 += 64) {
    // K: rows of Kb; V: pre-transposed 16B chunks from Vbt
    {
      const size_t krow = (size_t)(kv0 + j0) * MDIM + hofs;
      uint4 k0v = *(const uint4*)(Kb + krow + dq0 * 8);
      uint4 k1v = *(const uint4*)(Kb + krow + dq1 * 8);
      const size_t vbase = (((size_t)(kv0 >> 6) * NH + h) * HD) * 64;
      uint4 v0v = *(const uint4*)(Vbt + vbase + (size_t)dV0 * 64 + jo * 8);
      uint4 v1v = *(const uint4*)(Vbt + vbase + (size_t)dV1 * 64 + jo * 8);
      *(uint4*)&UN[j0 * 136 + dq0 * 8] = k0v;
      *(uint4*)&UN[j0 * 136 + dq1 * 8] = k1v;
      *(uint4*)&Vt[dV0][jo * 8] = v0v;
      *(uint4*)&Vt[dV1][jo * 8] = v1v;
    }
    __syncthreads();                                   // bar1: K/V staged

    f32x4 sa[4] = {};
#pragma unroll
    for (int ni = 0; ni < 4; ++ni)
#pragma unroll
      for (int kk = 0; kk < 4; ++kk) {
        bf16x8 bK = *(const bf16x8*)&UN[(ni * 16 + l16) * 136 + kk * 32 + kl * 8];
        sa[ni] = __builtin_amdgcn_mfma_f32_16x16x32_bf16(qf[kk], bK, sa[ni], 0, 0, 0);
      }
    __syncthreads();                                   // bar2: QK reads done (Pl aliases Kl)

    float sv[4][4];
    float pm[4] = {-1e30f, -1e30f, -1e30f, -1e30f};
#pragma unroll
    for (int ni = 0; ni < 4; ++ni) {
      int jg = kv0 + ni * 16 + l16;
      bool valid = jg < LTOT;
#pragma unroll
      for (int r = 0; r < 4; ++r) {
        float xs = valid ? sa[ni][r] * SCALE : -1e30f;
        sv[ni][r] = xs;
        pm[r] = fmaxf(pm[r], xs);
      }
    }
#pragma unroll
    for (int off = 1; off < 16; off <<= 1)
#pragma unroll
      for (int r = 0; r < 4; ++r) pm[r] = fmaxf(pm[r], __shfl_xor(pm[r], off));

    float sc[4];
#pragma unroll
    for (int r = 0; r < 4; ++r) {
      float mn = fmaxf(mrow[r], pm[r]);
      sc[r] = __expf(mrow[r] - mn);
      mrow[r] = mn;
    }
    float ps[4] = {0.f, 0.f, 0.f, 0.f};
#pragma unroll
    for (int ni = 0; ni < 4; ++ni)
#pragma unroll
      for (int r = 0; r < 4; ++r) {
        float p = __expf(sv[ni][r] - mrow[r]);
        sv[ni][r] = p;
        ps[r] += p;
      }
#pragma unroll
    for (int off = 1; off < 16; off <<= 1)
#pragma unroll
      for (int r = 0; r < 4; ++r) ps[r] += __shfl_xor(ps[r], off);
#pragma unroll
    for (int r = 0; r < 4; ++r) lrow[r] = lrow[r] * sc[r] + ps[r];
#pragma unroll
    for (int di = 0; di < 8; ++di)
#pragma unroll
      for (int r = 0; r < 4; ++r) oacc[di][r] *= sc[r];
#pragma unroll
    for (int ni = 0; ni < 4; ++ni)
#pragma unroll
      for (int r = 0; r < 4; ++r)
        UN[(wv * 16 + kl * 4 + r) * 72 + ni * 16 + l16] = (short)f2b(sv[ni][r]);
    __syncthreads();                                   // bar3: P staged

#pragma unroll
    for (int di = 0; di < 8; ++di)
#pragma unroll
      for (int k2 = 0; k2 < 2; ++k2) {
        bf16x8 aP = *(const bf16x8*)&UN[(wv * 16 + l16) * 72 + k2 * 32 + kl * 8];
        bf16x8 bV = *(const bf16x8*)&Vt[di * 16 + l16][k2 * 32 + kl * 8];
        oacc[di] = __builtin_amdgcn_mfma_f32_16x16x32_bf16(aP, bV, oacc[di], 0, 0, 0);
      }
    __syncthreads();                                   // bar4
  }

  const size_t pbase = (((size_t)z * NH + h) * NQT2 + qt);
  const int row = wv * 16 + kl * 4;
#pragma unroll
  for (int r = 0; r < 4; ++r) {
    unsigned short* Op = Opart + (pbase * 128 + row + r) * HD;
#pragma unroll
    for (int di = 0; di < 8; ++di) Op[di * 16 + l16] = f2b(oacc[di][r]);
    ml[(pbase * 2 + 0) * 128 + row + r] = mrow[r];
    ml[(pbase * 2 + 1) * 128 + row + r] = lrow[r];
  }
}

// ---------- merge bf16 partials -> bf16 O in Qb ----------
__global__ __launch_bounds__(512) void attn_merge3_k(
    const unsigned short* __restrict__ Opart, const float* __restrict__ ml,
    unsigned short* __restrict__ Qb, int S) {
  const int qt = blockIdx.x, h = blockIdx.y;
  const int t = threadIdx.x;
  const int row = t >> 2, d0 = (t & 3) * 32;
  const int q = qt * 128 + row;

  float M = -1e30f;
  for (int s = 0; s < S; ++s) {
    const size_t pbase = (((size_t)s * NH + h) * NQT2 + qt);
    M = fmaxf(M, ml[(pbase * 2 + 0) * 128 + row]);
  }
  float L = 0.f;
  float o[32];
#pragma unroll
  for (int i = 0; i < 32; ++i) o[i] = 0.f;
  for (int s = 0; s < S; ++s) {
    const size_t pbase = (((size_t)s * NH + h) * NQT2 + qt);
    const float ms = ml[(pbase * 2 + 0) * 128 + row];
    const float ls = ml[(pbase * 2 + 1) * 128 + row];
    const float w = __expf(ms - M);
    L += w * ls;
    const unsigned short* Op = Opart + (pbase * 128 + row) * HD + d0;
#pragma unroll
    for (int c = 0; c < 4; ++c) {
      bf16x8 v = *(const bf16x8*)(Op + c * 8);
#pragma unroll
      for (int i = 0; i < 8; ++i) o[c * 8 + i] += w * b2f((unsigned short)v[i]);
    }
  }
  if (q < SEQ) {
    const float inv = 1.f / L;
    unsigned short* op = Qb + ((size_t)h * SEQ + q) * HD + d0;
#pragma unroll
    for (int i = 0; i < 32; ++i) op[i] = f2b(o[i] * inv);
  }
}

extern "C" void kernel_launch(void* const* d_in, const int* in_sizes, int n_in,
                              void* d_out, int out_size, void* d_ws, size_t ws_size,
                              hipStream_t stream) {
  const float* x  = (const float*)d_in[0];
  const float* fr = (const float*)d_in[2];
  const float* Kc = (const float*)d_in[3];
  const float* Vc = (const float*)d_in[4];
  const float* Wq = (const float*)d_in[5];
  const float* bq = (const float*)d_in[6];
  const float* Wk = (const float*)d_in[7];
  const float* bk = (const float*)d_in[8];
  const float* Wv = (const float*)d_in[9];
  const float* bv = (const float*)d_in[10];
  const float* Wo = (const float*)d_in[11];
  const float* bo = (const float*)d_in[12];
  const float* gq = (const float*)d_in[13];
  const float* gk = (const float*)d_in[14];

  // ws: xb | Wto | Qb | Kb | Vbt | [Wtq Wtk Wtv -> partial-alias zone + tail]
  unsigned short* xb  = (unsigned short*)d_ws;
  unsigned short* Wto = xb + (size_t)SEQ * MDIM;
  unsigned short* Qb  = Wto + (size_t)MDIM * MDIM;
  unsigned short* Kb  = Qb + (size_t)NH * SEQ * HD;
  unsigned short* Vbt = Kb + (size_t)KROWS * MDIM;
  unsigned short* Wtq = Vbt + (size_t)NTILE * NH * HD * 64;
  unsigned short* Wtk = Wtq + (size_t)MDIM * MDIM;
  unsigned short* Wtv = Wtk + (size_t)MDIM * MDIM;

  const int S = SPLITS;  // fits in proven ws budget (>=128.3 MB from r20 S=8 tier)
  unsigned short* Opart = Wtq;  // aliases Wt zone (dead after gemm_qkv)
  float* ml = (float*)(Opart + (size_t)S * NH * NQT2 * 128 * HD);

  // zero Vbt tail tile (rows >= LTOT) so masked P=0 never meets NaN garbage
  hipMemsetAsync(Vbt + (size_t)(NTILE - 1) * NH * HD * 64, 0,
                 (size_t)NH * HD * 64 * 2, stream);

  const int n8x = SEQ * MDIM / 8;
  const int n8k = NCACHE * MDIM / 8;
  convx_k<<<dim3((n8x + 255) / 256), 256, 0, stream>>>(x, xb, n8x);
  convk_k<<<dim3((n8k + 255) / 256), 256, 0, stream>>>(Kc, Kb, n8k);
  convvt_k<<<dim3(NCACHE / 64, NH), 256, 0, stream>>>(Vc, Vbt);
  convt_k<<<dim3(32, 32, 4), 256, 0, stream>>>(Wq, Wk, Wv, Wo, Wtq, Wtk, Wtv, Wto);

  gemm_qkv_k<<<dim3(48, 17), 256, 0, stream>>>(xb, Wtq, Wtk, Wtv, bq, bk, bv, Qb, Kb, Vbt);
  rmsrope_k<<<dim3(SEQ, 2), 256, 0, stream>>>(Qb, Kb, gq, gk, fr);

  const int tiles = NTILE;                         // 147
  const int chunk = ((tiles + S - 1) / S) * 64;    // 25 tiles = 1600 rows
  attn_part7_k<<<dim3(NQT2 * NH * S), 512, 0, stream>>>(Qb, Kb, Vbt, Opart, ml, chunk, S);
  attn_merge3_k<<<dim3(NQT2, NH), 512, 0, stream>>>(Opart, ml, Qb, S);

  gemm_o_k<<<dim3(16, 17), 256, 0, stream>>>(Qb, Wto, bo, (float*)d_out);
}

// Round 23
// 397.790 us; speedup vs baseline: 1.3340x; 1.0191x over previous
//
#include <hip/hip_runtime.h>

using bf16x8 = __attribute__((ext_vector_type(8))) short;
using f32x4  = __attribute__((ext_vector_type(4))) float;

#define DEV static __device__ __forceinline__

constexpr int SEQ    = 1040;
constexpr int MDIM   = 2048;
constexpr int NH     = 16;
constexpr int HD     = 128;
constexpr int NCACHE = 8320;
constexpr int LTOT   = NCACHE + SEQ;   // 9360
constexpr int NTILE  = 147;            // ceil(LTOT/64)
constexpr int KROWS  = NTILE * 64;     // 9408
constexpr int NQT2   = 9;              // ceil(SEQ/128)
constexpr int SPLITS = 6;              // 864 blocks; 25 tiles/block

DEV float b2f(unsigned short u) {
  union { unsigned int i; float f; } z; z.i = ((unsigned int)u) << 16; return z.f;
}
DEV unsigned short f2b(float f) {
  union { float f; unsigned int i; } z; z.f = f;
  return (unsigned short)((z.i + 0x7fffu + ((z.i >> 16) & 1u)) >> 16);
}
DEV unsigned int cvtpk(float lo, float hi) {
  unsigned int r;
  asm("v_cvt_pk_bf16_f32 %0, %1, %2" : "=v"(r) : "v"(lo), "v"(hi));
  return r;
}
union U4S8 { uint4 u; short s[8]; };

// ---------- convert x fp32 -> bf16 ----------
__global__ __launch_bounds__(256) void convx_k(
    const float* __restrict__ x, unsigned short* __restrict__ xb, int n8) {
  int i = blockIdx.x * 256 + threadIdx.x;
  if (i < n8) {
    const float* p = x + (size_t)i * 8;
    f32x4 a = *(const f32x4*)p, b = *(const f32x4*)(p + 4);
    uint4 u = make_uint4(cvtpk(a[0], a[1]), cvtpk(a[2], a[3]),
                         cvtpk(b[0], b[1]), cvtpk(b[2], b[3]));
    *(uint4*)(xb + (size_t)i * 8) = u;
  }
}

// ---------- K cache fp32 -> bf16 flat ----------
__global__ __launch_bounds__(256) void convk_k(
    const float* __restrict__ Kc, unsigned short* __restrict__ Kb, int n8) {
  int i = blockIdx.x * 256 + threadIdx.x;
  if (i < n8) {
    const float* p = Kc + (size_t)i * 8;
    f32x4 a = *(const f32x4*)p, b = *(const f32x4*)(p + 4);
    uint4 u = make_uint4(cvtpk(a[0], a[1]), cvtpk(a[2], a[3]),
                         cvtpk(b[0], b[1]), cvtpk(b[2], b[3]));
    *(uint4*)(Kb + (size_t)i * 8) = u;
  }
}

// ---------- V cache fp32 -> bf16 pre-transposed Vbt[tile][h][d][j] ----------
__global__ __launch_bounds__(256) void convvt_k(
    const float* __restrict__ Vc, unsigned short* __restrict__ Vbt) {
  __shared__ short T[64][136];
  const int tile = blockIdx.x, h = blockIdx.y;
  const int t = threadIdx.x;
  {
    int row = t >> 2, cq = t & 3;
    const float* p = Vc + (size_t)(tile * 64 + row) * MDIM + h * HD + cq * 32;
#pragma unroll
    for (int k = 0; k < 4; ++k) {
      f32x4 a = *(const f32x4*)(p + k * 8);
      f32x4 b = *(const f32x4*)(p + k * 8 + 4);
      *(uint4*)&T[row][cq * 32 + k * 8] =
          make_uint4(cvtpk(a[0], a[1]), cvtpk(a[2], a[3]), cvtpk(b[0], b[1]), cvtpk(b[2], b[3]));
    }
  }
  __syncthreads();
#pragma unroll
  for (int i = 0; i < 4; ++i) {
    int c = t + i * 256;
    int d = c >> 3, joct = c & 7;
    U4S8 u;
#pragma unroll
    for (int jj = 0; jj < 8; ++jj) u.s[jj] = T[joct * 8 + jj][d];
    *(uint4*)(Vbt + ((((size_t)tile * NH + h) * HD + d) * 64 + joct * 8)) = u.u;
  }
}

// ---------- convert+transpose W [k][n] fp32 -> Wt [n][k] bf16 (4 weights) ----------
__global__ __launch_bounds__(256) void convt_k(
    const float* __restrict__ W0, const float* __restrict__ W1,
    const float* __restrict__ W2, const float* __restrict__ W3,
    unsigned short* __restrict__ T0, unsigned short* __restrict__ T1,
    unsigned short* __restrict__ T2, unsigned short* __restrict__ T3) {
  __shared__ short T[64][72];
  const int zz = blockIdx.z;
  const float* W = (zz == 0) ? W0 : (zz == 1) ? W1 : (zz == 2) ? W2 : W3;
  unsigned short* O = (zz == 0) ? T0 : (zz == 1) ? T1 : (zz == 2) ? T2 : T3;
  const int r0 = blockIdx.y * 64, c0 = blockIdx.x * 64;
  const int t = threadIdx.x;
  {
    int row = t >> 2, cq = t & 3;
    const float* p = W + (size_t)(r0 + row) * MDIM + c0 + cq * 16;
    f32x4 a = *(const f32x4*)(p);
    f32x4 b = *(const f32x4*)(p + 4);
    f32x4 c = *(const f32x4*)(p + 8);
    f32x4 d = *(const f32x4*)(p + 12);
    *(uint4*)&T[row][cq * 16] =
        make_uint4(cvtpk(a[0], a[1]), cvtpk(a[2], a[3]), cvtpk(b[0], b[1]), cvtpk(b[2], b[3]));
    *(uint4*)&T[row][cq * 16 + 8] =
        make_uint4(cvtpk(c[0], c[1]), cvtpk(c[2], c[3]), cvtpk(d[0], d[1]), cvtpk(d[2], d[3]));
  }
  __syncthreads();
  {
    int c = t >> 2, kq = t & 3;
    U4S8 v0, v1;
#pragma unroll
    for (int i = 0; i < 8; ++i) v0.s[i] = T[kq * 16 + i][c];
#pragma unroll
    for (int i = 0; i < 8; ++i) v1.s[i] = T[kq * 16 + 8 + i][c];
    unsigned short* op = O + (size_t)(c0 + c) * MDIM + r0 + kq * 16;
    *(uint4*)(op) = v0.u;
    *(uint4*)(op + 8) = v1.u;
  }
}

// ---------- fused QKV GEMM (r22, passing) ----------
__global__ __launch_bounds__(256) void gemm_qkv_k(
    const unsigned short* __restrict__ xb,
    const unsigned short* __restrict__ Wtq, const unsigned short* __restrict__ Wtk,
    const unsigned short* __restrict__ Wtv,
    const float* __restrict__ bq, const float* __restrict__ bk, const float* __restrict__ bv,
    unsigned short* __restrict__ Qb, unsigned short* __restrict__ Kb, unsigned short* __restrict__ Vbt) {
  __shared__ short As[64][72];
  __shared__ short Bs[128][72];
  const int tid = threadIdx.x;
  const int l = tid & 63, wv = tid >> 6;
  const int l16 = l & 15, kl = l >> 4;
  const int m0 = blockIdx.y * 64;
  const int n0g = blockIdx.x * 128;
  const int which = n0g >> 11;
  const int n0 = n0g & 2047;
  const unsigned short* Wt = (which == 0) ? Wtq : (which == 1) ? Wtk : Wtv;
  const float* bias = (which == 0) ? bq : (which == 1) ? bk : bv;
  const int wm = (wv >> 1) * 32, wn = (wv & 1) * 64;
  f32x4 acc[2][4] = {};
  for (int k0 = 0; k0 < MDIM; k0 += 64) {
    {
      int m = tid >> 2, kq = tid & 3;
      int row = m0 + m;
      uint4 v0 = make_uint4(0, 0, 0, 0), v1 = make_uint4(0, 0, 0, 0);
      if (row < SEQ) {
        const unsigned short* p = xb + (size_t)row * MDIM + k0 + kq * 16;
        v0 = *(const uint4*)p;
        v1 = *(const uint4*)(p + 8);
      }
      *(uint4*)&As[m][kq * 16] = v0;
      *(uint4*)&As[m][kq * 16 + 8] = v1;
    }
    {
      int n = tid >> 1, kq = tid & 1;
      const unsigned short* p = Wt + (size_t)(n0 + n) * MDIM + k0 + kq * 32;
      uint4 v0 = *(const uint4*)p, v1 = *(const uint4*)(p + 8);
      uint4 v2 = *(const uint4*)(p + 16), v3 = *(const uint4*)(p + 24);
      *(uint4*)&Bs[n][kq * 32] = v0;
      *(uint4*)&Bs[n][kq * 32 + 8] = v1;
      *(uint4*)&Bs[n][kq * 32 + 16] = v2;
      *(uint4*)&Bs[n][kq * 32 + 24] = v3;
    }
    __syncthreads();
#pragma unroll
    for (int kk = 0; kk < 2; ++kk) {
      bf16x8 aF[2], bF[4];
#pragma unroll
      for (int mi = 0; mi < 2; ++mi)
        aF[mi] = *(const bf16x8*)&As[wm + mi * 16 + l16][kk * 32 + kl * 8];
#pragma unroll
      for (int ni = 0; ni < 4; ++ni)
        bF[ni] = *(const bf16x8*)&Bs[wn + ni * 16 + l16][kk * 32 + kl * 8];
#pragma unroll
      for (int mi = 0; mi < 2; ++mi)
#pragma unroll
        for (int ni = 0; ni < 4; ++ni)
          acc[mi][ni] = __builtin_amdgcn_mfma_f32_16x16x32_bf16(
              aF[mi], bF[ni], acc[mi][ni], 0, 0, 0);
    }
    __syncthreads();
  }
#pragma unroll
  for (int ni = 0; ni < 4; ++ni) {
    const int col = n0 + wn + ni * 16 + l16;
    const float bb = bias[col];
    const int hh = col >> 7, dd = col & 127;
#pragma unroll
    for (int mi = 0; mi < 2; ++mi) {
      const int rowb = m0 + wm + mi * 16 + kl * 4;
#pragma unroll
      for (int r = 0; r < 4; ++r) {
        const int row = rowb + r;
        if (row >= SEQ) continue;
        const unsigned short val = f2b(acc[mi][ni][r] + bb);
        if (which == 0) {
          Qb[((size_t)hh * SEQ + row) * HD + dd] = val;
        } else if (which == 1) {
          Kb[(size_t)(NCACHE + row) * MDIM + col] = val;
        } else {
          const int g = NCACHE + row;
          Vbt[(((size_t)(g >> 6) * NH + hh) * HD + dd) * 64 + (g & 63)] = val;
        }
      }
    }
  }
}

// ---------- Wo GEMM (r20, passing) ----------
__global__ __launch_bounds__(256) void gemm_o_k(
    const unsigned short* __restrict__ Ab, const unsigned short* __restrict__ Wt,
    const float* __restrict__ bias, float* __restrict__ outp) {
  __shared__ short As[64][72];
  __shared__ short Bs[128][72];
  const int tid = threadIdx.x;
  const int l = tid & 63, wv = tid >> 6;
  const int l16 = l & 15, kl = l >> 4;
  const int m0 = blockIdx.y * 64, n0 = blockIdx.x * 128;
  const int wm = (wv >> 1) * 32, wn = (wv & 1) * 64;
  f32x4 acc[2][4] = {};
  for (int k0 = 0; k0 < MDIM; k0 += 64) {
    {
      int m = tid >> 2, kq = tid & 3;
      int row = m0 + m, k = k0 + kq * 16;
      uint4 v0 = make_uint4(0, 0, 0, 0), v1 = make_uint4(0, 0, 0, 0);
      if (row < SEQ) {
        const unsigned short* p = Ab + ((size_t)(k >> 7) * SEQ + row) * HD + (k & 127);
        v0 = *(const uint4*)p;
        v1 = *(const uint4*)(p + 8);
      }
      *(uint4*)&As[m][kq * 16] = v0;
      *(uint4*)&As[m][kq * 16 + 8] = v1;
    }
    {
      int n = tid >> 1, kq = tid & 1;
      const unsigned short* p = Wt + (size_t)(n0 + n) * MDIM + k0 + kq * 32;
      uint4 v0 = *(const uint4*)p, v1 = *(const uint4*)(p + 8);
      uint4 v2 = *(const uint4*)(p + 16), v3 = *(const uint4*)(p + 24);
      *(uint4*)&Bs[n][kq * 32] = v0;
      *(uint4*)&Bs[n][kq * 32 + 8] = v1;
      *(uint4*)&Bs[n][kq * 32 + 16] = v2;
      *(uint4*)&Bs[n][kq * 32 + 24] = v3;
    }
    __syncthreads();
#pragma unroll
    for (int kk = 0; kk < 2; ++kk) {
      bf16x8 aF[2], bF[4];
#pragma unroll
      for (int mi = 0; mi < 2; ++mi)
        aF[mi] = *(const bf16x8*)&As[wm + mi * 16 + l16][kk * 32 + kl * 8];
#pragma unroll
      for (int ni = 0; ni < 4; ++ni)
        bF[ni] = *(const bf16x8*)&Bs[wn + ni * 16 + l16][kk * 32 + kl * 8];
#pragma unroll
      for (int mi = 0; mi < 2; ++mi)
#pragma unroll
        for (int ni = 0; ni < 4; ++ni)
          acc[mi][ni] = __builtin_amdgcn_mfma_f32_16x16x32_bf16(
              aF[mi], bF[ni], acc[mi][ni], 0, 0, 0);
    }
    __syncthreads();
  }
#pragma unroll
  for (int ni = 0; ni < 4; ++ni) {
    const int col = n0 + wn + ni * 16 + l16;
    const float bb = bias[col];
#pragma unroll
    for (int mi = 0; mi < 2; ++mi) {
      const int rowb = m0 + wm + mi * 16 + kl * 4;
#pragma unroll
      for (int r = 0; r < 4; ++r) {
        const int row = rowb + r;
        if (row >= SEQ) continue;
        outp[(size_t)row * MDIM + col] = acc[mi][ni][r] + bb;
      }
    }
  }
}

// ---------- RMSNorm + RoPE (r22, passing) ----------
__global__ __launch_bounds__(256) void rmsrope_k(
    unsigned short* __restrict__ Qb, unsigned short* __restrict__ Kb,
    const float* __restrict__ gq, const float* __restrict__ gk,
    const float* __restrict__ fr) {
  const int s = blockIdx.x, which = blockIdx.y;
  const float* g = which ? gk : gq;
  __shared__ float cs[64], sn[64], red[4];
  const int t = threadIdx.x;
  if (t < 64) {
    float a = fr[s * 64 + t];
    cs[t] = cosf(a);
    sn[t] = sinf(a);
  }
  const int c0 = t * 8;
  const int hh = c0 >> 7, dd = c0 & 127, p0 = dd >> 1;
  unsigned short* ptr = which
      ? Kb + (size_t)(NCACHE + s) * MDIM + c0
      : Qb + ((size_t)hh * SEQ + s) * HD + dd;
  bf16x8 v = *(const bf16x8*)ptr;
  float y[8];
#pragma unroll
  for (int i = 0; i < 8; ++i) y[i] = b2f((unsigned short)v[i]);
  float ssq = 0.f;
#pragma unroll
  for (int i = 0; i < 8; ++i) ssq += y[i] * y[i];
#pragma unroll
  for (int off = 32; off; off >>= 1) ssq += __shfl_xor(ssq, off);
  if ((t & 63) == 0) red[t >> 6] = ssq;
  __syncthreads();
  const float var = (red[0] + red[1] + red[2] + red[3]) * (1.0f / MDIM);
  const float rs = rsqrtf(var + 1e-6f);
  bf16x8 ov;
#pragma unroll
  for (int i = 0; i < 4; ++i) {
    float e = b2f(f2b(y[2 * i] * rs)) * g[c0 + 2 * i];
    float o = b2f(f2b(y[2 * i + 1] * rs)) * g[c0 + 2 * i + 1];
    float C = cs[p0 + i], S = sn[p0 + i];
    ov[2 * i]     = (short)f2b(e * C - o * S);
    ov[2 * i + 1] = (short)f2b(e * S + o * C);
  }
  *(bf16x8*)ptr = ov;
}

// ---------- flash attention v8: 3 barriers (bar3 removed; wave-private P),
//            setprio around MFMA clusters, defer-max THR=8 ----------
__global__ __launch_bounds__(512) void attn_part8_k(
    const unsigned short* __restrict__ Qb, const unsigned short* __restrict__ Kb,
    const unsigned short* __restrict__ Vbt, unsigned short* __restrict__ Opart,
    float* __restrict__ ml, int chunk, int S) {
  __shared__ short UN[9216];        // Kl: UN[j*136+d]; Pl: UN[(w*16+r)*72+c] (aliased, wave-private slabs)
  __shared__ short Vt[128][72];
  const int b = blockIdx.x;
  const int xcd = b & 7;
  const int r_ = b >> 3;
  const int qt = r_ % NQT2;
  const int g = (r_ / NQT2) * 8 + xcd;
  const int h = g & (NH - 1);
  const int z = g >> 4;
  const int tid = threadIdx.x, wv = tid >> 6, l = tid & 63;
  const int l16 = l & 15, kl = l >> 4;
  const float SCALE = 0.08838834764831845f;

  const int c0 = z * chunk;
  const int cend = min(c0 + chunk, LTOT);

  int qrow = qt * 128 + wv * 16 + l16;
  if (qrow > SEQ - 1) qrow = SEQ - 1;
  bf16x8 qf[4];
#pragma unroll
  for (int kk = 0; kk < 4; ++kk)
    qf[kk] = *(const bf16x8*)(Qb + ((size_t)h * SEQ + qrow) * HD + kk * 32 + kl * 8);

  f32x4 oacc[8] = {};
  float mrow[4] = {-1e30f, -1e30f, -1e30f, -1e30f};
  float lrow[4] = {0.f, 0.f, 0.f, 0.f};

  const int j0 = tid & 63, dq0 = tid >> 6, dq1 = (tid + 512) >> 6;
  const int dV0 = tid >> 3, dV1 = (tid + 512) >> 3, jo = tid & 7;
  const int hofs = h * HD;

  for (int kv0 = c0; kv0 < cend; kv0 += 64) {
    {
      const size_t krow = (size_t)(kv0 + j0) * MDIM + hofs;
      uint4 k0v = *(const uint4*)(Kb + krow + dq0 * 8);
      uint4 k1v = *(const uint4*)(Kb + krow + dq1 * 8);
      const size_t vbase = (((size_t)(kv0 >> 6) * NH + h) * HD) * 64;
      uint4 v0v = *(const uint4*)(Vbt + vbase + (size_t)dV0 * 64 + jo * 8);
      uint4 v1v = *(const uint4*)(Vbt + vbase + (size_t)dV1 * 64 + jo * 8);
      *(uint4*)&UN[j0 * 136 + dq0 * 8] = k0v;
      *(uint4*)&UN[j0 * 136 + dq1 * 8] = k1v;
      *(uint4*)&Vt[dV0][jo * 8] = v0v;
      *(uint4*)&Vt[dV1][jo * 8] = v1v;
    }
    __syncthreads();                                   // bar1: K/V staged

    f32x4 sa[4] = {};
    __builtin_amdgcn_s_setprio(1);
#pragma unroll
    for (int ni = 0; ni < 4; ++ni)
#pragma unroll
      for (int kk = 0; kk < 4; ++kk) {
        bf16x8 bK = *(const bf16x8*)&UN[(ni * 16 + l16) * 136 + kk * 32 + kl * 8];
        sa[ni] = __builtin_amdgcn_mfma_f32_16x16x32_bf16(qf[kk], bK, sa[ni], 0, 0, 0);
      }
    __builtin_amdgcn_s_setprio(0);
    __syncthreads();                                   // bar2: QK reads done (P aliases Kl)

    float sv[4][4];
    float pm[4] = {-1e30f, -1e30f, -1e30f, -1e30f};
#pragma unroll
    for (int ni = 0; ni < 4; ++ni) {
      int jg = kv0 + ni * 16 + l16;
      bool valid = jg < LTOT;
#pragma unroll
      for (int r = 0; r < 4; ++r) {
        float xs = valid ? sa[ni][r] * SCALE : -1e30f;
        sv[ni][r] = xs;
        pm[r] = fmaxf(pm[r], xs);
      }
    }
#pragma unroll
    for (int off = 1; off < 16; off <<= 1)
#pragma unroll
      for (int r = 0; r < 4; ++r) pm[r] = fmaxf(pm[r], __shfl_xor(pm[r], off));

    // T13 defer-max: only rescale when some row max grew by > 8
    bool grow = (pm[0] > mrow[0] + 8.f) || (pm[1] > mrow[1] + 8.f) ||
                (pm[2] > mrow[2] + 8.f) || (pm[3] > mrow[3] + 8.f);
    if (__any(grow)) {
#pragma unroll
      for (int r = 0; r < 4; ++r) {
        float mn = fmaxf(mrow[r], pm[r]);
        float sc = __expf(mrow[r] - mn);
        mrow[r] = mn;
        lrow[r] *= sc;
#pragma unroll
        for (int di = 0; di < 8; ++di) oacc[di][r] *= sc;
      }
    }

    float ps[4] = {0.f, 0.f, 0.f, 0.f};
#pragma unroll
    for (int ni = 0; ni < 4; ++ni)
#pragma unroll
      for (int r = 0; r < 4; ++r) {
        float p = __expf(sv[ni][r] - mrow[r]);   // bounded by e^8
        sv[ni][r] = p;
        ps[r] += p;
      }
#pragma unroll
    for (int off = 1; off < 16; off <<= 1)
#pragma unroll
      for (int r = 0; r < 4; ++r) ps[r] += __shfl_xor(ps[r], off);
#pragma unroll
    for (int r = 0; r < 4; ++r) lrow[r] += ps[r];

    // P write into own wave slab (wave-private; same-wave read below, no barrier)
#pragma unroll
    for (int ni = 0; ni < 4; ++ni)
#pragma unroll
      for (int r = 0; r < 4; ++r)
        UN[(wv * 16 + kl * 4 + r) * 72 + ni * 16 + l16] = (short)f2b(sv[ni][r]);

    __builtin_amdgcn_s_setprio(1);
#pragma unroll
    for (int di = 0; di < 8; ++di)
#pragma unroll
      for (int k2 = 0; k2 < 2; ++k2) {
        bf16x8 aP = *(const bf16x8*)&UN[(wv * 16 + l16) * 72 + k2 * 32 + kl * 8];
        bf16x8 bV = *(const bf16x8*)&Vt[di * 16 + l16][k2 * 32 + kl * 8];
        oacc[di] = __builtin_amdgcn_mfma_f32_16x16x32_bf16(aP, bV, oacc[di], 0, 0, 0);
      }
    __builtin_amdgcn_s_setprio(0);
    __syncthreads();                                   // bar3: all reads done; UN/Vt free
  }

  const size_t pbase = (((size_t)z * NH + h) * NQT2 + qt);
  const int row = wv * 16 + kl * 4;
#pragma unroll
  for (int r = 0; r < 4; ++r) {
    unsigned short* Op = Opart + (pbase * 128 + row + r) * HD;
#pragma unroll
    for (int di = 0; di < 8; ++di) Op[di * 16 + l16] = f2b(oacc[di][r]);
    ml[(pbase * 2 + 0) * 128 + row + r] = mrow[r];
    ml[(pbase * 2 + 1) * 128 + row + r] = lrow[r];
  }
}

// ---------- merge bf16 partials -> bf16 O in Qb (r21, passing) ----------
__global__ __launch_bounds__(512) void attn_merge3_k(
    const unsigned short* __restrict__ Opart, const float* __restrict__ ml,
    unsigned short* __restrict__ Qb, int S) {
  const int qt = blockIdx.x, h = blockIdx.y;
  const int t = threadIdx.x;
  const int row = t >> 2, d0 = (t & 3) * 32;
  const int q = qt * 128 + row;

  float M = -1e30f;
  for (int s = 0; s < S; ++s) {
    const size_t pbase = (((size_t)s * NH + h) * NQT2 + qt);
    M = fmaxf(M, ml[(pbase * 2 + 0) * 128 + row]);
  }
  float L = 0.f;
  float o[32];
#pragma unroll
  for (int i = 0; i < 32; ++i) o[i] = 0.f;
  for (int s = 0; s < S; ++s) {
    const size_t pbase = (((size_t)s * NH + h) * NQT2 + qt);
    const float ms = ml[(pbase * 2 + 0) * 128 + row];
    const float ls = ml[(pbase * 2 + 1) * 128 + row];
    const float w = __expf(ms - M);
    L += w * ls;
    const unsigned short* Op = Opart + (pbase * 128 + row) * HD + d0;
#pragma unroll
    for (int c = 0; c < 4; ++c) {
      bf16x8 v = *(const bf16x8*)(Op + c * 8);
#pragma unroll
      for (int i = 0; i < 8; ++i) o[c * 8 + i] += w * b2f((unsigned short)v[i]);
    }
  }
  if (q < SEQ) {
    const float inv = 1.f / L;
    unsigned short* op = Qb + ((size_t)h * SEQ + q) * HD + d0;
#pragma unroll
    for (int i = 0; i < 32; ++i) op[i] = f2b(o[i] * inv);
  }
}

extern "C" void kernel_launch(void* const* d_in, const int* in_sizes, int n_in,
                              void* d_out, int out_size, void* d_ws, size_t ws_size,
                              hipStream_t stream) {
  const float* x  = (const float*)d_in[0];
  const float* fr = (const float*)d_in[2];
  const float* Kc = (const float*)d_in[3];
  const float* Vc = (const float*)d_in[4];
  const float* Wq = (const float*)d_in[5];
  const float* bq = (const float*)d_in[6];
  const float* Wk = (const float*)d_in[7];
  const float* bk = (const float*)d_in[8];
  const float* Wv = (const float*)d_in[9];
  const float* bv = (const float*)d_in[10];
  const float* Wo = (const float*)d_in[11];
  const float* bo = (const float*)d_in[12];
  const float* gq = (const float*)d_in[13];
  const float* gk = (const float*)d_in[14];

  unsigned short* xb  = (unsigned short*)d_ws;
  unsigned short* Wto = xb + (size_t)SEQ * MDIM;
  unsigned short* Qb  = Wto + (size_t)MDIM * MDIM;
  unsigned short* Kb  = Qb + (size_t)NH * SEQ * HD;
  unsigned short* Vbt = Kb + (size_t)KROWS * MDIM;
  unsigned short* Wtq = Vbt + (size_t)NTILE * NH * HD * 64;
  unsigned short* Wtk = Wtq + (size_t)MDIM * MDIM;
  unsigned short* Wtv = Wtk + (size_t)MDIM * MDIM;

  const int S = SPLITS;
  unsigned short* Opart = Wtq;   // aliases Wt zone (dead after gemm_qkv)
  float* ml = (float*)(Opart + (size_t)S * NH * NQT2 * 128 * HD);

  hipMemsetAsync(Vbt + (size_t)(NTILE - 1) * NH * HD * 64, 0,
                 (size_t)NH * HD * 64 * 2, stream);

  const int n8x = SEQ * MDIM / 8;
  const int n8k = NCACHE * MDIM / 8;
  convx_k<<<dim3((n8x + 255) / 256), 256, 0, stream>>>(x, xb, n8x);
  convk_k<<<dim3((n8k + 255) / 256), 256, 0, stream>>>(Kc, Kb, n8k);
  convvt_k<<<dim3(NCACHE / 64, NH), 256, 0, stream>>>(Vc, Vbt);
  convt_k<<<dim3(32, 32, 4), 256, 0, stream>>>(Wq, Wk, Wv, Wo, Wtq, Wtk, Wtv, Wto);

  gemm_qkv_k<<<dim3(48, 17), 256, 0, stream>>>(xb, Wtq, Wtk, Wtv, bq, bk, bv, Qb, Kb, Vbt);
  rmsrope_k<<<dim3(SEQ, 2), 256, 0, stream>>>(Qb, Kb, gq, gk, fr);

  const int chunk = ((NTILE + S - 1) / S) * 64;    // 25 tiles
  attn_part8_k<<<dim3(NQT2 * NH * S), 512, 0, stream>>>(Qb, Kb, Vbt, Opart, ml, chunk, S);
  attn_merge3_k<<<dim3(NQT2, NH), 512, 0, stream>>>(Opart, ml, Qb, S);

  gemm_o_k<<<dim3(16, 17), 256, 0, stream>>>(Qb, Wto, bo, (float*)d_out);
}